// Round 1
// baseline (3218.166 us; speedup 1.0000x reference)
//
#include <hip/hip_runtime.h>
#include <hip/hip_bf16.h>

#define C 256
#define HID 128
#define Bb_ 2
#define Hh 64
#define Ww 64
#define Nn_ 4096
#define NP 16
#define NC 16

// ---------------------------------------------------------------------------
// LayerNorm over channels (per position), producing both ln1 and ln2 outputs.
// grid = B*N blocks, block = 256 threads (one per channel)
__global__ __launch_bounds__(256) void ln_dual_kernel(
    const float* __restrict__ x,
    const float* __restrict__ g1, const float* __restrict__ b1,
    const float* __restrict__ g2, const float* __restrict__ b2,
    float* __restrict__ x1, float* __restrict__ x2)
{
    long bn = blockIdx.x;
    long b = bn / Nn_, n = bn % Nn_;
    int c = threadIdx.x;
    long idx = (long)b * C * Nn_ + (long)c * Nn_ + n;
    float v = x[idx];
    __shared__ float rs[256], rq[256];
    rs[c] = v; rq[c] = v * v;
    __syncthreads();
    for (int s = 128; s > 0; s >>= 1) {
        if (c < s) { rs[c] += rs[c + s]; rq[c] += rq[c + s]; }
        __syncthreads();
    }
    float mean = rs[0] * (1.0f / C);
    float var = rq[0] * (1.0f / C) - mean * mean;
    float inv = rsqrtf(var + 1e-5f);
    float xn = (v - mean) * inv;
    x1[idx] = xn * g1[c] + b1[c];
    x2[idx] = xn * g2[c] + b2[c];
}

// ---------------------------------------------------------------------------
// gate[b,o] = sigmoid(bg[o] + sum_c mean_p(arch[b,p,c]) * Wg[o,c])
// grid = B, block = 256
__global__ __launch_bounds__(256) void gate_kernel(
    const float* __restrict__ arch, const float* __restrict__ Wg,
    const float* __restrict__ bg, float* __restrict__ gate)
{
    int b = blockIdx.x;
    int o = threadIdx.x;
    __shared__ float guide[C];
    float s = 0.f;
    for (int p = 0; p < NP; ++p) s += arch[(long)b * NP * C + (long)p * C + o];
    guide[o] = s * (1.0f / NP);
    __syncthreads();
    float acc = bg[o];
    for (int cc = 0; cc < C; ++cc) acc += guide[cc] * Wg[(long)o * C + cc];
    gate[b * C + o] = 1.0f / (1.0f + __expf(-acc));
}

// ---------------------------------------------------------------------------
// k_s *= gate (in-place inside qkv buffer). total = B*C*N threads
__global__ __launch_bounds__(256) void mul_gate_kernel(
    float* __restrict__ qkv, const float* __restrict__ gate)
{
    long i = (long)blockIdx.x * 256 + threadIdx.x;
    if (i >= (long)Bb_ * C * Nn_) return;
    long b = i / ((long)C * Nn_);
    long c = (i / Nn_) % C;
    long n = i % Nn_;
    long idx = b * (3l * C * Nn_) + (C + c) * (long)Nn_ + n;
    qkv[idx] *= gate[b * C + c];
}

// ---------------------------------------------------------------------------
// Generic fp32 GEMM: C[m,n] = alpha * sum_k A[m*sAm + k*sAk] * B[k*sBk + n*sBn]
//                    (+ bias[m]) (+ resid same layout as C)
// block 256 threads -> 64x64 tile, 4x4 per thread, TK=16
#define TM 64
#define TN 64
#define TK 16
__global__ __launch_bounds__(256) void gemm_generic(
    const float* __restrict__ A, const float* __restrict__ Bm, float* __restrict__ Cm,
    int M, int Nd, int K,
    long sAm, long sAk, long bA,
    long sBk, long sBn, long bB,
    long sCm, long sCn, long bC,
    const float* __restrict__ bias,
    const float* __restrict__ resid, long bR,
    float alpha)
{
    __shared__ float As[TK][TM + 4];
    __shared__ float Bs[TK][TN + 4];
    int bz = blockIdx.z;
    const float* Ab = A + (long)bz * bA;
    const float* Bbp = Bm + (long)bz * bB;
    float* Cb = Cm + (long)bz * bC;
    int m0 = blockIdx.y * TM;
    int n0 = blockIdx.x * TN;
    int tid = threadIdx.x;
    int tx = tid % 16, ty = tid / 16;
    float acc[4][4] = {};
    for (int k0 = 0; k0 < K; k0 += TK) {
        for (int l = tid; l < TM * TK; l += 256) {
            int mm = l / TK, kk = l % TK;
            int gm = m0 + mm, gk = k0 + kk;
            float v = (gm < M) ? Ab[(long)gm * sAm + (long)gk * sAk] : 0.f;
            As[kk][mm] = v;
        }
        for (int l = tid; l < TK * TN; l += 256) {
            int kk = l / TN, nn = l % TN;
            int gn = n0 + nn, gk = k0 + kk;
            float v = (gn < Nd) ? Bbp[(long)gk * sBk + (long)gn * sBn] : 0.f;
            Bs[kk][nn] = v;
        }
        __syncthreads();
        #pragma unroll
        for (int kk = 0; kk < TK; ++kk) {
            float a[4], bv[4];
            #pragma unroll
            for (int i = 0; i < 4; ++i) a[i] = As[kk][ty * 4 + i];
            #pragma unroll
            for (int j = 0; j < 4; ++j) bv[j] = Bs[kk][tx * 4 + j];
            #pragma unroll
            for (int i = 0; i < 4; ++i)
                #pragma unroll
                for (int j = 0; j < 4; ++j)
                    acc[i][j] += a[i] * bv[j];
        }
        __syncthreads();
    }
    for (int i = 0; i < 4; ++i) {
        int gm = m0 + ty * 4 + i;
        if (gm >= M) continue;
        float bvv = bias ? bias[gm] : 0.f;
        for (int j = 0; j < 4; ++j) {
            int gn = n0 + tx * 4 + j;
            if (gn >= Nd) continue;
            float v = acc[i][j] * alpha + bvv;
            if (resid) v += resid[(long)bz * bR + (long)gm * sCm + (long)gn * sCn];
            Cb[(long)gm * sCm + (long)gn * sCn] = v;
        }
    }
}

// ---------------------------------------------------------------------------
// Row softmax, in-place. grid = #rows, block = 256
__global__ __launch_bounds__(256) void softmax_rows(float* __restrict__ a, int rowlen)
{
    long row = blockIdx.x;
    float* p = a + row * (long)rowlen;
    int tid = threadIdx.x;
    __shared__ float red[256];
    float mx = -1e30f;
    for (int i = tid; i < rowlen; i += 256) mx = fmaxf(mx, p[i]);
    red[tid] = mx; __syncthreads();
    for (int s = 128; s > 0; s >>= 1) {
        if (tid < s) red[tid] = fmaxf(red[tid], red[tid + s]);
        __syncthreads();
    }
    mx = red[0]; __syncthreads();
    float sum = 0.f;
    for (int i = tid; i < rowlen; i += 256) {
        float e = __expf(p[i] - mx);
        p[i] = e; sum += e;
    }
    red[tid] = sum; __syncthreads();
    for (int s = 128; s > 0; s >>= 1) {
        if (tid < s) red[tid] += red[tid + s];
        __syncthreads();
    }
    float inv = 1.0f / red[0];
    for (int i = tid; i < rowlen; i += 256) p[i] *= inv;
}

// ---------------------------------------------------------------------------
// kv = ctx @ Wkv^T + bkv, stored transposed: kvc[b][0][h][i]=k, [b][1][h][i]=v
// grid = B*NC, block = 256 (thread j over 2*HID outputs)
__global__ __launch_bounds__(256) void kv_proj_kernel(
    const float* __restrict__ ctx, const float* __restrict__ Wkv,
    const float* __restrict__ bkv, float* __restrict__ kvc)
{
    int b = blockIdx.x / NC, i = blockIdx.x % NC;
    int j = threadIdx.x;
    const float* cv = ctx + ((long)b * NC + i) * C;
    __shared__ float cs[C];
    cs[j] = cv[j];
    __syncthreads();
    float acc = bkv[j];
    for (int cc = 0; cc < C; ++cc) acc += cs[cc] * Wkv[(long)j * C + cc];
    int half = j / HID, h = j % HID;
    kvc[((long)b * 2 + half) * HID * NC + (long)h * NC + i] = acc;
}

// ---------------------------------------------------------------------------
// Cross attention: per position n -> softmax over 16 contextuals, PV.
// grid = B*N/256, block = 256 (one thread per position; b uniform per block)
__global__ __launch_bounds__(256) void cross_attn_kernel(
    const float* __restrict__ qc, const float* __restrict__ kvc,
    float* __restrict__ refc)
{
    long gi = (long)blockIdx.x * 256 + threadIdx.x;
    long b = gi / Nn_, n = gi % Nn_;
    __shared__ float kl[HID][NC], vl[HID][NC];
    const float* kb = kvc + b * 2l * HID * NC;
    for (int l = threadIdx.x; l < HID * NC; l += 256) {
        kl[l / NC][l % NC] = kb[l];
        vl[l / NC][l % NC] = kb[HID * NC + l];
    }
    __syncthreads();
    float s[NC];
    #pragma unroll
    for (int m = 0; m < NC; ++m) s[m] = 0.f;
    for (int h = 0; h < HID; ++h) {
        float qh = qc[b * (long)HID * Nn_ + (long)h * Nn_ + n];
        #pragma unroll
        for (int m = 0; m < NC; ++m) s[m] += qh * kl[h][m];
    }
    const float sc = 0.08838834764831845f; // 1/sqrt(128)
    float mx = -1e30f;
    #pragma unroll
    for (int m = 0; m < NC; ++m) { s[m] *= sc; mx = fmaxf(mx, s[m]); }
    float sum = 0.f;
    #pragma unroll
    for (int m = 0; m < NC; ++m) { s[m] = __expf(s[m] - mx); sum += s[m]; }
    float inv = 1.0f / sum;
    for (int h = 0; h < HID; ++h) {
        float acc = 0.f;
        #pragma unroll
        for (int m = 0; m < NC; ++m) acc += vl[h][m] * s[m];
        refc[b * (long)HID * Nn_ + (long)h * Nn_ + n] = acc * inv;
    }
}

// ---------------------------------------------------------------------------
// Direct 3x3 conv over 512 input channels (concat[out_self, out_cross]), ReLU.
// grid = (W/16, H/16, B*C), block = 256 = 16x16 spatial tile, one out channel.
#define ICT 8
__global__ __launch_bounds__(256) void conv3x3_relu_kernel(
    const float* __restrict__ outself, const float* __restrict__ outcross,
    const float* __restrict__ Wf1, float* __restrict__ y1)
{
    int bz = blockIdx.z;
    int b = bz / C, o = bz % C;
    int w0 = blockIdx.x * 16, h0 = blockIdx.y * 16;
    int tx = threadIdx.x % 16, ty = threadIdx.x / 16;
    __shared__ float patch[ICT][18][19];
    float acc = 0.f;
    for (int i0 = 0; i0 < 2 * C; i0 += ICT) {
        for (int l = threadIdx.x; l < ICT * 18 * 18; l += 256) {
            int ic = l / 324;
            int rem = l % 324;
            int r = rem / 18, cc = rem % 18;
            int gh = h0 - 1 + r, gw = w0 - 1 + cc;
            int ich = i0 + ic;
            float v = 0.f;
            if (gh >= 0 && gh < Hh && gw >= 0 && gw < Ww) {
                const float* src = (ich < C) ? outself : outcross;
                int ch = (ich < C) ? ich : ich - C;
                v = src[((long)b * C + ch) * Nn_ + (long)gh * Ww + gw];
            }
            patch[ic][r][cc] = v;
        }
        __syncthreads();
        #pragma unroll
        for (int ic = 0; ic < ICT; ++ic) {
            const float* wp = Wf1 + ((long)o * (2 * C) + (i0 + ic)) * 9;
            #pragma unroll
            for (int kh = 0; kh < 3; ++kh)
                #pragma unroll
                for (int kw = 0; kw < 3; ++kw)
                    acc += wp[kh * 3 + kw] * patch[ic][ty + kh][tx + kw];
        }
        __syncthreads();
    }
    y1[((long)b * C + o) * Nn_ + (long)(h0 + ty) * Ww + (w0 + tx)] = fmaxf(acc, 0.f);
}

// ---------------------------------------------------------------------------
extern "C" void kernel_launch(void* const* d_in, const int* in_sizes, int n_in,
                              void* d_out, int out_size, void* d_ws, size_t ws_size,
                              hipStream_t stream)
{
    const float* qry   = (const float*)d_in[0];
    const float* arch  = (const float*)d_in[1];
    const float* ctx   = (const float*)d_in[2];
    const float* ln1_g = (const float*)d_in[3];
    const float* ln1_b = (const float*)d_in[4];
    const float* Wqkv  = (const float*)d_in[5];
    const float* bqkv  = (const float*)d_in[6];
    const float* Wproj = (const float*)d_in[7];
    const float* bproj = (const float*)d_in[8];
    const float* Wg    = (const float*)d_in[9];
    const float* bg    = (const float*)d_in[10];
    const float* ln2_g = (const float*)d_in[11];
    const float* ln2_b = (const float*)d_in[12];
    const float* Wq    = (const float*)d_in[13];
    const float* bq    = (const float*)d_in[14];
    const float* Wkv   = (const float*)d_in[15];
    const float* bkv   = (const float*)d_in[16];
    const float* Wout  = (const float*)d_in[17];
    const float* bout  = (const float*)d_in[18];
    const float* Wf1   = (const float*)d_in[19];
    const float* Wf2   = (const float*)d_in[20];
    const float* bf2   = (const float*)d_in[21];
    float* out = (float*)d_out;

    const long CN = (long)C * Nn_;      // 1,048,576
    float* ws = (float*)d_ws;
    long off = 0;
    float* x1      = ws + off; off += Bb_ * CN;
    float* x2      = ws + off; off += Bb_ * CN;
    float* qkv     = ws + off; off += Bb_ * 3 * CN;
    float* gate    = ws + off; off += Bb_ * C;
    float* attn    = ws + off; off += (long)Nn_ * Nn_;   // per-batch reuse
    float* refs    = ws + off; off += Bb_ * CN;
    float* outself = ws + off; off += Bb_ * CN;
    float* qc      = ws + off; off += (long)Bb_ * HID * Nn_;
    float* kvc     = ws + off; off += (long)Bb_ * 2 * HID * NC;
    float* refc    = ws + off; off += (long)Bb_ * HID * Nn_;
    float* outcross= ws + off; off += Bb_ * CN;
    float* y1      = ws + off; off += Bb_ * CN;

    // 1. dual layernorm
    ln_dual_kernel<<<Bb_ * Nn_, 256, 0, stream>>>(qry, ln1_g, ln1_b, ln2_g, ln2_b, x1, x2);

    // 2. gate
    gate_kernel<<<Bb_, 256, 0, stream>>>(arch, Wg, bg, gate);

    // 3. qkv = Wqkv @ x1 + bqkv   [B, 768, N]
    gemm_generic<<<dim3(Nn_ / TN, (3 * C) / TM, Bb_), 256, 0, stream>>>(
        Wqkv, x1, qkv, 3 * C, Nn_, C,
        C, 1, 0,            // A strides
        Nn_, 1, CN,         // B strides
        Nn_, 1, 3 * CN,     // C strides
        bqkv, nullptr, 0, 1.0f);

    // 4. fold gate into k_s
    mul_gate_kernel<<<(Bb_ * CN + 255) / 256, 256, 0, stream>>>(qkv, gate);

    // 5-7. self attention per batch (attn buffer reused)
    for (int b = 0; b < Bb_; ++b) {
        const float* q_s = qkv + (long)b * 3 * CN;
        const float* k_s = q_s + CN;
        const float* v_s = q_s + 2 * CN;
        // scores: attn[n,m] = (1/16) * sum_c q[c,n]*k_g[c,m]
        gemm_generic<<<dim3(Nn_ / TN, Nn_ / TM, 1), 256, 0, stream>>>(
            q_s, k_s, attn, Nn_, Nn_, C,
            1, Nn_, 0,
            Nn_, 1, 0,
            Nn_, 1, 0,
            nullptr, nullptr, 0, 0.0625f);
        softmax_rows<<<Nn_, 256, 0, stream>>>(attn, Nn_);
        // PV: refs[c,n] = sum_m v[c,m]*attn[n,m]
        gemm_generic<<<dim3(Nn_ / TN, C / TM, 1), 256, 0, stream>>>(
            v_s, attn, refs + (long)b * CN, C, Nn_, Nn_,
            Nn_, 1, 0,
            1, Nn_, 0,
            Nn_, 1, 0,
            nullptr, nullptr, 0, 1.0f);
    }

    // 8. out_self = qry + Wproj @ refs + bproj
    gemm_generic<<<dim3(Nn_ / TN, C / TM, Bb_), 256, 0, stream>>>(
        Wproj, refs, outself, C, Nn_, C,
        C, 1, 0,
        Nn_, 1, CN,
        Nn_, 1, CN,
        bproj, qry, CN, 1.0f);

    // 9. q_c = Wq @ x2 + bq  [B, 128, N]
    gemm_generic<<<dim3(Nn_ / TN, HID / TM, Bb_), 256, 0, stream>>>(
        Wq, x2, qc, HID, Nn_, C,
        C, 1, 0,
        Nn_, 1, CN,
        Nn_, 1, (long)HID * Nn_,
        bq, nullptr, 0, 1.0f);

    // 10. kv projection of contextuals
    kv_proj_kernel<<<Bb_ * NC, 256, 0, stream>>>(ctx, Wkv, bkv, kvc);

    // 11. cross attention -> refc [B, HID, N]
    cross_attn_kernel<<<(Bb_ * Nn_) / 256, 256, 0, stream>>>(qc, kvc, refc);

    // 12. out_cross = qry + Wout @ refc + bout
    gemm_generic<<<dim3(Nn_ / TN, C / TM, Bb_), 256, 0, stream>>>(
        Wout, refc, outcross, C, Nn_, HID,
        HID, 1, 0,
        Nn_, 1, (long)HID * Nn_,
        Nn_, 1, CN,
        bout, qry, CN, 1.0f);

    // 13. conv3x3 over concat channels + ReLU
    conv3x3_relu_kernel<<<dim3(Ww / 16, Hh / 16, Bb_ * C), 256, 0, stream>>>(
        outself, outcross, Wf1, y1);

    // 14. out = qry + Wf2 @ y1 + bf2   (1x1 conv)
    gemm_generic<<<dim3(Nn_ / TN, C / TM, Bb_), 256, 0, stream>>>(
        Wf2, y1, out, C, Nn_, C,
        C, 1, 0,
        Nn_, 1, CN,
        Nn_, 1, CN,
        bf2, qry, CN, 1.0f);
}

// Round 2
// 859.672 us; speedup vs baseline: 3.7435x; 3.7435x over previous
//
#include <hip/hip_runtime.h>
#include <hip/hip_bf16.h>

#define C 256
#define HID 128
#define Bb_ 2
#define Hh 64
#define Ww 64
#define Nn_ 4096
#define NP 16
#define NC 16

typedef __bf16 bf16x8 __attribute__((ext_vector_type(8)));
typedef float f32x4 __attribute__((ext_vector_type(4)));

// ---------------------------------------------------------------------------
// LayerNorm over channels; writes x1^T as bf16 [B][N][C] (for MFMA Bt operand)
// and x2 as fp32 [B][C][N] (for the fp32 generic Wq GEMM).
__global__ __launch_bounds__(256) void ln_dual_kernel(
    const float* __restrict__ x,
    const float* __restrict__ g1, const float* __restrict__ b1,
    const float* __restrict__ g2, const float* __restrict__ b2,
    __hip_bfloat16* __restrict__ x1T, float* __restrict__ x2)
{
    long bn = blockIdx.x;
    long b = bn / Nn_, n = bn % Nn_;
    int c = threadIdx.x;
    long idx = (long)b * C * Nn_ + (long)c * Nn_ + n;
    float v = x[idx];
    __shared__ float rs[256], rq[256];
    rs[c] = v; rq[c] = v * v;
    __syncthreads();
    for (int s = 128; s > 0; s >>= 1) {
        if (c < s) { rs[c] += rs[c + s]; rq[c] += rq[c + s]; }
        __syncthreads();
    }
    float mean = rs[0] * (1.0f / C);
    float var = rq[0] * (1.0f / C) - mean * mean;
    float inv = rsqrtf(var + 1e-5f);
    float xn = (v - mean) * inv;
    x1T[((long)b * Nn_ + n) * C + c] = __float2bfloat16(xn * g1[c] + b1[c]);
    x2[idx] = xn * g2[c] + b2[c];
}

// ---------------------------------------------------------------------------
__global__ __launch_bounds__(256) void gate_kernel(
    const float* __restrict__ arch, const float* __restrict__ Wg,
    const float* __restrict__ bg, float* __restrict__ gate)
{
    int b = blockIdx.x;
    int o = threadIdx.x;
    __shared__ float guide[C];
    float s = 0.f;
    for (int p = 0; p < NP; ++p) s += arch[(long)b * NP * C + (long)p * C + o];
    guide[o] = s * (1.0f / NP);
    __syncthreads();
    float acc = bg[o];
    for (int cc = 0; cc < C; ++cc) acc += guide[cc] * Wg[(long)o * C + cc];
    gate[b * C + o] = 1.0f / (1.0f + __expf(-acc));
}

// ---------------------------------------------------------------------------
// fp32 -> bf16 elementwise cast
__global__ __launch_bounds__(256) void cast_f2b(
    const float* __restrict__ in, __hip_bfloat16* __restrict__ out, long n)
{
    long i = (long)blockIdx.x * 256 + threadIdx.x;
    if (i < n) out[i] = __float2bfloat16(in[i]);
}

// ---------------------------------------------------------------------------
// MFMA bf16 GEMM:  D[m][n] = alpha * sum_k A[m][k] * Bt[n][k]  (+bias[m]) (+resid) (relu)
// A: [M][K] bf16 row-major (lda=K). Bt: [N][K] bf16 row-major (ldb=K). D: fp32 [M][N].
// 128x128 tile, BK=32, 4 waves (2x2), each wave 64x64 via 4x4 16x16x32 MFMA frags.
// M, N multiples of 128; K multiple of 32.
__global__ __launch_bounds__(256) void gemm_bt(
    const __hip_bfloat16* __restrict__ A,
    const __hip_bfloat16* __restrict__ Bt,
    float* __restrict__ D,
    int M, int N, int K,
    long batchA, long batchB, long batchD,
    const float* __restrict__ bias,
    const float* __restrict__ resid, long batchR,
    float alpha, int relu)
{
    __shared__ __align__(16) __hip_bfloat16 As[128 * 32];
    __shared__ __align__(16) __hip_bfloat16 Bs[128 * 32];
    int bz = blockIdx.z;
    const __hip_bfloat16* Ab = A + (long)bz * batchA;
    const __hip_bfloat16* Bb = Bt + (long)bz * batchB;
    int m0 = blockIdx.y * 128, n0 = blockIdx.x * 128;
    int tid = threadIdx.x;
    int lane = tid & 63, wave = tid >> 6;
    int wr = wave >> 1, wc = wave & 1;
    int lr = lane & 15, lg = lane >> 4;

    f32x4 acc[4][4];
    #pragma unroll
    for (int i = 0; i < 4; ++i)
        #pragma unroll
        for (int j = 0; j < 4; ++j)
            #pragma unroll
            for (int r = 0; r < 4; ++r) acc[i][j][r] = 0.f;

    for (int k0 = 0; k0 < K; k0 += 32) {
        // stage A/B tiles: [128][32] bf16 each = 8KB, 512 x 16B
        #pragma unroll
        for (int q = 0; q < 2; ++q) {
            int idx = q * 256 + tid;           // 0..511
            int row = idx >> 2;                // 0..127
            int ke = (idx & 3) * 8;            // k element offset (x8 bf16 = 16B)
            uint4 va = *(const uint4*)(Ab + (long)(m0 + row) * K + k0 + ke);
            uint4 vb = *(const uint4*)(Bb + (long)(n0 + row) * K + k0 + ke);
            ((uint4*)As)[idx] = va;
            ((uint4*)Bs)[idx] = vb;
        }
        __syncthreads();
        bf16x8 af[4], bf[4];
        #pragma unroll
        for (int i = 0; i < 4; ++i) {
            int r = wr * 64 + i * 16 + lr;
            af[i] = *(const bf16x8*)(As + r * 32 + lg * 8);
        }
        #pragma unroll
        for (int j = 0; j < 4; ++j) {
            int cidx = wc * 64 + j * 16 + lr;
            bf[j] = *(const bf16x8*)(Bs + cidx * 32 + lg * 8);
        }
        #pragma unroll
        for (int i = 0; i < 4; ++i)
            #pragma unroll
            for (int j = 0; j < 4; ++j)
                acc[i][j] = __builtin_amdgcn_mfma_f32_16x16x32_bf16(af[i], bf[j], acc[i][j], 0, 0, 0);
        __syncthreads();
    }

    float* Db = D + (long)bz * batchD;
    int colb = n0 + wc * 64 + lr;
    #pragma unroll
    for (int i = 0; i < 4; ++i) {
        #pragma unroll
        for (int r = 0; r < 4; ++r) {
            int row = m0 + wr * 64 + i * 16 + lg * 4 + r;
            float bv = bias ? bias[row] : 0.f;
            #pragma unroll
            for (int j = 0; j < 4; ++j) {
                int cc = colb + j * 16;
                float v = acc[i][j][r] * alpha + bv;
                if (resid) v += resid[(long)bz * batchR + (long)row * N + cc];
                if (relu) v = fmaxf(v, 0.f);
                Db[(long)row * N + cc] = v;
            }
        }
    }
}

// ---------------------------------------------------------------------------
// From qkv fp32 [B][768][N]: qT[n][c] bf16, kT[n][c] bf16 (gate folded), v[c][n] bf16.
// grid (N/64, C/64, B), 256 threads, 64x64 LDS transpose tiles.
__global__ __launch_bounds__(256) void extract_qkv(
    const float* __restrict__ qkv, const float* __restrict__ gate,
    __hip_bfloat16* __restrict__ qT, __hip_bfloat16* __restrict__ kT,
    __hip_bfloat16* __restrict__ vB)
{
    int b = blockIdx.z;
    int c0 = blockIdx.y * 64, n0 = blockIdx.x * 64;
    __shared__ float t[64][65];
    const float* base = qkv + (long)b * 3 * C * Nn_;
    int tx = threadIdx.x & 63, tg = threadIdx.x >> 6;

    for (int rr = tg; rr < 64; rr += 4)
        t[rr][tx] = base[(long)(c0 + rr) * Nn_ + n0 + tx];
    __syncthreads();
    for (int rr = tg; rr < 64; rr += 4)
        qT[((long)b * Nn_ + n0 + rr) * C + c0 + tx] = __float2bfloat16(t[tx][rr]);
    __syncthreads();

    for (int rr = tg; rr < 64; rr += 4)
        t[rr][tx] = base[(long)(C + c0 + rr) * Nn_ + n0 + tx] * gate[b * C + c0 + rr];
    __syncthreads();
    for (int rr = tg; rr < 64; rr += 4)
        kT[((long)b * Nn_ + n0 + rr) * C + c0 + tx] = __float2bfloat16(t[tx][rr]);

    for (int rr = tg; rr < 64; rr += 4)
        vB[((long)b * C + c0 + rr) * Nn_ + n0 + tx] =
            __float2bfloat16(base[(long)(2 * C + c0 + rr) * Nn_ + n0 + tx]);
}

// ---------------------------------------------------------------------------
// Row softmax with LDS row cache; fp32 in -> bf16 out. grid = 4096, block 256.
__global__ __launch_bounds__(256) void softmax_rows_bf16(
    const float* __restrict__ S, __hip_bfloat16* __restrict__ P)
{
    __shared__ float row[Nn_];
    __shared__ float red[256];
    long r = blockIdx.x;
    const float* p = S + r * (long)Nn_;
    int t = threadIdx.x;
    float mx = -1e30f;
    for (int j = 0; j < Nn_ / 256; ++j) {
        float v = p[j * 256 + t];
        row[j * 256 + t] = v;
        mx = fmaxf(mx, v);
    }
    red[t] = mx; __syncthreads();
    for (int s = 128; s > 0; s >>= 1) {
        if (t < s) red[t] = fmaxf(red[t], red[t + s]);
        __syncthreads();
    }
    mx = red[0]; __syncthreads();
    float sum = 0.f;
    for (int j = 0; j < Nn_ / 256; ++j) {
        float e = __expf(row[j * 256 + t] - mx);
        row[j * 256 + t] = e; sum += e;
    }
    red[t] = sum; __syncthreads();
    for (int s = 128; s > 0; s >>= 1) {
        if (t < s) red[t] += red[t + s];
        __syncthreads();
    }
    float inv = 1.0f / red[0];
    for (int j = 0; j < Nn_ / 256; ++j)
        P[r * (long)Nn_ + j * 256 + t] = __float2bfloat16(row[j * 256 + t] * inv);
}

// ---------------------------------------------------------------------------
// im2col (per batch): col[n][ic*9 + kh*3 + kw] = padded input, bf16.
// grid = 4096 (one position), 256 threads loop K=4608.
__global__ __launch_bounds__(256) void im2col_kernel(
    const float* __restrict__ os, const float* __restrict__ oc,
    __hip_bfloat16* __restrict__ col)
{
    int n = blockIdx.x;
    int h = n >> 6, w = n & 63;
    for (int k = threadIdx.x; k < 2 * C * 9; k += 256) {
        int ic = k / 9, tap = k % 9;
        int kh = tap / 3, kw = tap % 3;
        int gh = h + kh - 1, gw = w + kw - 1;
        float v = 0.f;
        if ((unsigned)gh < (unsigned)Hh && (unsigned)gw < (unsigned)Ww) {
            const float* src = (ic < C) ? os : oc;
            int ch = ic & (C - 1);
            v = src[(long)ch * Nn_ + gh * Ww + gw];
        }
        col[(long)n * (2 * C * 9) + k] = __float2bfloat16(v);
    }
}

// ---------------------------------------------------------------------------
// Generic fp32 GEMM (round-0, proven) for the small projections.
#define TM 64
#define TN 64
#define TK 16
__global__ __launch_bounds__(256) void gemm_generic(
    const float* __restrict__ A, const float* __restrict__ Bm, float* __restrict__ Cm,
    int M, int Nd, int K,
    long sAm, long sAk, long bA,
    long sBk, long sBn, long bB,
    long sCm, long sCn, long bC,
    const float* __restrict__ bias,
    const float* __restrict__ resid, long bR,
    float alpha)
{
    __shared__ float As[TK][TM + 4];
    __shared__ float Bs[TK][TN + 4];
    int bz = blockIdx.z;
    const float* Ab = A + (long)bz * bA;
    const float* Bbp = Bm + (long)bz * bB;
    float* Cb = Cm + (long)bz * bC;
    int m0 = blockIdx.y * TM;
    int n0 = blockIdx.x * TN;
    int tid = threadIdx.x;
    int tx = tid % 16, ty = tid / 16;
    float acc[4][4] = {};
    for (int k0 = 0; k0 < K; k0 += TK) {
        for (int l = tid; l < TM * TK; l += 256) {
            int mm = l / TK, kk = l % TK;
            int gm = m0 + mm, gk = k0 + kk;
            float v = (gm < M) ? Ab[(long)gm * sAm + (long)gk * sAk] : 0.f;
            As[kk][mm] = v;
        }
        for (int l = tid; l < TK * TN; l += 256) {
            int kk = l / TN, nn = l % TN;
            int gn = n0 + nn, gk = k0 + kk;
            float v = (gn < Nd) ? Bbp[(long)gk * sBk + (long)gn * sBn] : 0.f;
            Bs[kk][nn] = v;
        }
        __syncthreads();
        #pragma unroll
        for (int kk = 0; kk < TK; ++kk) {
            float a[4], bv[4];
            #pragma unroll
            for (int i = 0; i < 4; ++i) a[i] = As[kk][ty * 4 + i];
            #pragma unroll
            for (int j = 0; j < 4; ++j) bv[j] = Bs[kk][tx * 4 + j];
            #pragma unroll
            for (int i = 0; i < 4; ++i)
                #pragma unroll
                for (int j = 0; j < 4; ++j)
                    acc[i][j] += a[i] * bv[j];
        }
        __syncthreads();
    }
    for (int i = 0; i < 4; ++i) {
        int gm = m0 + ty * 4 + i;
        if (gm >= M) continue;
        float bvv = bias ? bias[gm] : 0.f;
        for (int j = 0; j < 4; ++j) {
            int gn = n0 + tx * 4 + j;
            if (gn >= Nd) continue;
            float v = acc[i][j] * alpha + bvv;
            if (resid) v += resid[(long)bz * bR + (long)gm * sCm + (long)gn * sCn];
            Cb[(long)gm * sCm + (long)gn * sCn] = v;
        }
    }
}

// ---------------------------------------------------------------------------
__global__ __launch_bounds__(256) void kv_proj_kernel(
    const float* __restrict__ ctx, const float* __restrict__ Wkv,
    const float* __restrict__ bkv, float* __restrict__ kvc)
{
    int b = blockIdx.x / NC, i = blockIdx.x % NC;
    int j = threadIdx.x;
    const float* cv = ctx + ((long)b * NC + i) * C;
    __shared__ float cs[C];
    cs[j] = cv[j];
    __syncthreads();
    float acc = bkv[j];
    for (int cc = 0; cc < C; ++cc) acc += cs[cc] * Wkv[(long)j * C + cc];
    int half = j / HID, h = j % HID;
    kvc[((long)b * 2 + half) * HID * NC + (long)h * NC + i] = acc;
}

__global__ __launch_bounds__(256) void cross_attn_kernel(
    const float* __restrict__ qc, const float* __restrict__ kvc,
    float* __restrict__ refc)
{
    long gi = (long)blockIdx.x * 256 + threadIdx.x;
    long b = gi / Nn_, n = gi % Nn_;
    __shared__ float kl[HID][NC], vl[HID][NC];
    const float* kb = kvc + b * 2l * HID * NC;
    for (int l = threadIdx.x; l < HID * NC; l += 256) {
        kl[l / NC][l % NC] = kb[l];
        vl[l / NC][l % NC] = kb[HID * NC + l];
    }
    __syncthreads();
    float s[NC];
    #pragma unroll
    for (int m = 0; m < NC; ++m) s[m] = 0.f;
    for (int h = 0; h < HID; ++h) {
        float qh = qc[b * (long)HID * Nn_ + (long)h * Nn_ + n];
        #pragma unroll
        for (int m = 0; m < NC; ++m) s[m] += qh * kl[h][m];
    }
    const float sc = 0.08838834764831845f;
    float mx = -1e30f;
    #pragma unroll
    for (int m = 0; m < NC; ++m) { s[m] *= sc; mx = fmaxf(mx, s[m]); }
    float sum = 0.f;
    #pragma unroll
    for (int m = 0; m < NC; ++m) { s[m] = __expf(s[m] - mx); sum += s[m]; }
    float inv = 1.0f / sum;
    for (int h = 0; h < HID; ++h) {
        float acc = 0.f;
        #pragma unroll
        for (int m = 0; m < NC; ++m) acc += vl[h][m] * s[m];
        refc[b * (long)HID * Nn_ + (long)h * Nn_ + n] = acc * inv;
    }
}

// ---------------------------------------------------------------------------
extern "C" void kernel_launch(void* const* d_in, const int* in_sizes, int n_in,
                              void* d_out, int out_size, void* d_ws, size_t ws_size,
                              hipStream_t stream)
{
    const float* qry   = (const float*)d_in[0];
    const float* arch  = (const float*)d_in[1];
    const float* ctx   = (const float*)d_in[2];
    const float* ln1_g = (const float*)d_in[3];
    const float* ln1_b = (const float*)d_in[4];
    const float* Wqkv  = (const float*)d_in[5];
    const float* bqkv  = (const float*)d_in[6];
    const float* Wproj = (const float*)d_in[7];
    const float* bproj = (const float*)d_in[8];
    const float* Wg    = (const float*)d_in[9];
    const float* bg    = (const float*)d_in[10];
    const float* ln2_g = (const float*)d_in[11];
    const float* ln2_b = (const float*)d_in[12];
    const float* Wq    = (const float*)d_in[13];
    const float* bq    = (const float*)d_in[14];
    const float* Wkv   = (const float*)d_in[15];
    const float* bkv   = (const float*)d_in[16];
    const float* Wout  = (const float*)d_in[17];
    const float* bout  = (const float*)d_in[18];
    const float* Wf1   = (const float*)d_in[19];
    const float* Wf2   = (const float*)d_in[20];
    const float* bf2   = (const float*)d_in[21];
    float* out = (float*)d_out;

    const long CN = (long)C * Nn_;      // 1,048,576
    const long NCb = (long)Nn_ * C;     // same count, [N][C] layout
    char* ws = (char*)d_ws;
    size_t off = 0;
    auto alloc = [&](size_t bytes) -> char* {
        char* p = ws + off;
        off += (bytes + 255) & ~size_t(255);
        return p;
    };
    float* x2       = (float*)alloc(Bb_ * CN * 4);
    float* qkv      = (float*)alloc(Bb_ * 3 * CN * 4);
    float* gate     = (float*)alloc(Bb_ * C * 4);
    float* refs     = (float*)alloc(Bb_ * CN * 4);
    float* outself  = (float*)alloc(Bb_ * CN * 4);
    float* qc       = (float*)alloc((long)Bb_ * HID * Nn_ * 4);
    float* kvc      = (float*)alloc((long)Bb_ * 2 * HID * NC * 4);
    float* refc     = (float*)alloc((long)Bb_ * HID * Nn_ * 4);
    float* outcross = (float*)alloc(Bb_ * CN * 4);
    float* y1       = (float*)alloc(Bb_ * CN * 4);
    float* S        = (float*)alloc((long)Nn_ * Nn_ * 4);     // also reused as im2col col buf
    __hip_bfloat16* x1T   = (__hip_bfloat16*)alloc(Bb_ * NCb * 2);
    __hip_bfloat16* qT    = (__hip_bfloat16*)alloc(Bb_ * NCb * 2);
    __hip_bfloat16* kT    = (__hip_bfloat16*)alloc(Bb_ * NCb * 2);
    __hip_bfloat16* vB    = (__hip_bfloat16*)alloc(Bb_ * CN * 2);
    __hip_bfloat16* P     = (__hip_bfloat16*)alloc((long)Nn_ * Nn_ * 2);
    __hip_bfloat16* Wqkvb = (__hip_bfloat16*)alloc((long)3 * C * C * 2);
    __hip_bfloat16* Wf1b  = (__hip_bfloat16*)alloc((long)C * 2 * C * 9 * 2);
    __hip_bfloat16* colb  = (__hip_bfloat16*)S;               // alias: S dead before conv

    // 1. dual layernorm (x1 -> transposed bf16)
    ln_dual_kernel<<<Bb_ * Nn_, 256, 0, stream>>>(qry, ln1_g, ln1_b, ln2_g, ln2_b, x1T, x2);

    // 2. gate
    gate_kernel<<<Bb_, 256, 0, stream>>>(arch, Wg, bg, gate);

    // 3. weight casts
    cast_f2b<<<(3 * C * C + 255) / 256, 256, 0, stream>>>(Wqkv, Wqkvb, (long)3 * C * C);
    cast_f2b<<<((long)C * 2 * C * 9 + 255) / 256, 256, 0, stream>>>(Wf1, Wf1b, (long)C * 2 * C * 9);

    // 4. qkv = Wqkv @ x1 + bqkv  [B][768][N]  (MFMA)
    gemm_bt<<<dim3(Nn_ / 128, (3 * C) / 128, Bb_), 256, 0, stream>>>(
        Wqkvb, x1T, qkv, 3 * C, Nn_, C,
        0, NCb, 3 * CN, bqkv, nullptr, 0, 1.0f, 0);

    // 5. extract qT, kT (gated), v bf16
    extract_qkv<<<dim3(Nn_ / 64, C / 64, Bb_), 256, 0, stream>>>(qkv, gate, qT, kT, vB);

    // 6. self attention per batch
    for (int b = 0; b < Bb_; ++b) {
        gemm_bt<<<dim3(Nn_ / 128, Nn_ / 128, 1), 256, 0, stream>>>(
            qT + (long)b * NCb, kT + (long)b * NCb, S, Nn_, Nn_, C,
            0, 0, 0, nullptr, nullptr, 0, 0.0625f, 0);
        softmax_rows_bf16<<<Nn_, 256, 0, stream>>>(S, P);
        gemm_bt<<<dim3(Nn_ / 128, C / 128, 1), 256, 0, stream>>>(
            vB + (long)b * CN, P, refs + (long)b * CN, C, Nn_, Nn_,
            0, 0, 0, nullptr, nullptr, 0, 1.0f, 0);
    }

    // 7. out_self = qry + Wproj @ refs + bproj  (fp32 generic)
    gemm_generic<<<dim3(Nn_ / TN, C / TM, Bb_), 256, 0, stream>>>(
        Wproj, refs, outself, C, Nn_, C,
        C, 1, 0, Nn_, 1, CN, Nn_, 1, CN, bproj, qry, CN, 1.0f);

    // 8. q_c = Wq @ x2 + bq
    gemm_generic<<<dim3(Nn_ / TN, HID / TM, Bb_), 256, 0, stream>>>(
        Wq, x2, qc, HID, Nn_, C,
        C, 1, 0, Nn_, 1, CN, Nn_, 1, (long)HID * Nn_, bq, nullptr, 0, 1.0f);

    // 9. kv projection + cross attention
    kv_proj_kernel<<<Bb_ * NC, 256, 0, stream>>>(ctx, Wkv, bkv, kvc);
    cross_attn_kernel<<<(Bb_ * Nn_) / 256, 256, 0, stream>>>(qc, kvc, refc);

    // 10. out_cross = qry + Wout @ refc + bout
    gemm_generic<<<dim3(Nn_ / TN, C / TM, Bb_), 256, 0, stream>>>(
        Wout, refc, outcross, C, Nn_, HID,
        HID, 1, 0, Nn_, 1, (long)HID * Nn_, Nn_, 1, CN, bout, qry, CN, 1.0f);

    // 11. conv3x3 + ReLU via im2col + MFMA GEMM (per batch; col aliases S)
    for (int b = 0; b < Bb_; ++b) {
        im2col_kernel<<<Nn_, 256, 0, stream>>>(
            outself + (long)b * CN, outcross + (long)b * CN, colb);
        gemm_bt<<<dim3(Nn_ / 128, C / 128, 1), 256, 0, stream>>>(
            Wf1b, colb, y1 + (long)b * CN, C, Nn_, 2 * C * 9,
            0, 0, 0, nullptr, nullptr, 0, 1.0f, 1);
    }

    // 12. out = qry + Wf2 @ y1 + bf2
    gemm_generic<<<dim3(Nn_ / TN, C / TM, Bb_), 256, 0, stream>>>(
        Wf2, y1, out, C, Nn_, C,
        C, 1, 0, Nn_, 1, CN, Nn_, 1, CN, bf2, qry, CN, 1.0f);
}

// Round 3
// 476.654 us; speedup vs baseline: 6.7516x; 1.8036x over previous
//
#include <hip/hip_runtime.h>
#include <hip/hip_bf16.h>

#define C 256
#define HID 128
#define Bb_ 2
#define Hh 64
#define Ww 64
#define Nn_ 4096
#define NP 16
#define NC 16

typedef __bf16 bf16x8 __attribute__((ext_vector_type(8)));
typedef float f32x4 __attribute__((ext_vector_type(4)));

// ---------------------------------------------------------------------------
// Coalesced tiled LayerNorm: block = 64 positions x 256 channels.
// Reads x [B][C][N] coalesced (64 consecutive n per wave), stages bf16 in LDS,
// writes x1T/x2T [B][N][C] bf16 coalesced.
__global__ __launch_bounds__(256) void lnT_kernel(
    const float* __restrict__ x,
    const float* __restrict__ g1, const float* __restrict__ b1,
    const float* __restrict__ g2, const float* __restrict__ b2,
    __hip_bfloat16* __restrict__ x1T, __hip_bfloat16* __restrict__ x2T)
{
    int blk = blockIdx.x;
    int b = blk >> 6;                 // Nn_/64 = 64 tiles per batch
    int n0 = (blk & 63) << 6;
    int t = threadIdx.x;
    __shared__ __hip_bfloat16 xs[64][258];   // [pos][chan], pad->conflict-free
    __shared__ float rs4[4][64], rq4[4][64], mean[64], inv[64];
    int j = t & 63, cg = t >> 6;
    float s = 0.f, q = 0.f;
    for (int it = 0; it < 64; ++it) {
        int c = it * 4 + cg;
        float v = x[((long)b * C + c) * Nn_ + n0 + j];
        xs[j][c] = __float2bfloat16(v);
        s += v; q += v * v;
    }
    rs4[cg][j] = s; rq4[cg][j] = q;
    __syncthreads();
    if (t < 64) {
        float S = rs4[0][t] + rs4[1][t] + rs4[2][t] + rs4[3][t];
        float Q = rq4[0][t] + rq4[1][t] + rq4[2][t] + rq4[3][t];
        float m = S * (1.0f / C);
        float var = Q * (1.0f / C) - m * m;
        mean[t] = m; inv[t] = rsqrtf(var + 1e-5f);
    }
    __syncthreads();
    float G1 = g1[t], B1 = b1[t], G2 = g2[t], B2 = b2[t];
    for (int j2 = 0; j2 < 64; ++j2) {
        float v = __bfloat162float(xs[j2][t]);
        float xn = (v - mean[j2]) * inv[j2];
        long o = ((long)b * Nn_ + n0 + j2) * C + t;
        x1T[o] = __float2bfloat16(xn * G1 + B1);
        x2T[o] = __float2bfloat16(xn * G2 + B2);
    }
}

// ---------------------------------------------------------------------------
__global__ __launch_bounds__(256) void gate_kernel(
    const float* __restrict__ arch, const float* __restrict__ Wg,
    const float* __restrict__ bg, float* __restrict__ gate)
{
    int b = blockIdx.x;
    int o = threadIdx.x;
    __shared__ float guide[C];
    float s = 0.f;
    for (int p = 0; p < NP; ++p) s += arch[(long)b * NP * C + (long)p * C + o];
    guide[o] = s * (1.0f / NP);
    __syncthreads();
    float acc = bg[o];
    for (int cc = 0; cc < C; ++cc) acc += guide[cc] * Wg[(long)o * C + cc];
    gate[b * C + o] = 1.0f / (1.0f + __expf(-acc));
}

// ---------------------------------------------------------------------------
// Per-batch gated Wqkv (bf16) + per-batch column bias (k-part scaled by gate).
__global__ __launch_bounds__(256) void build_wqkv(
    const float* __restrict__ Wqkv, const float* __restrict__ bqkv,
    const float* __restrict__ gate,
    __hip_bfloat16* __restrict__ WqkvG, float* __restrict__ biasCol)
{
    long i = (long)blockIdx.x * 256 + threadIdx.x;
    long total = (long)Bb_ * 3 * C * C;
    if (i < total) {
        long b = i / (3 * C * C);
        long rem = i % (3 * C * C);
        int o = (int)(rem / C);
        float v = Wqkv[rem];
        if (o >= C && o < 2 * C) v *= gate[b * C + (o - C)];
        WqkvG[i] = __float2bfloat16(v);
    }
    if (i < (long)Bb_ * 3 * C) {
        long b = i / (3 * C);
        int o = (int)(i % (3 * C));
        float v = bqkv[o];
        if (o >= C && o < 2 * C) v *= gate[b * C + (o - C)];
        biasCol[i] = v;
    }
}

// ---------------------------------------------------------------------------
__global__ __launch_bounds__(256) void cast_f2b(
    const float* __restrict__ in, __hip_bfloat16* __restrict__ out, long n)
{
    long i = (long)blockIdx.x * 256 + threadIdx.x;
    if (i < n) out[i] = __float2bfloat16(in[i]);
}

// ---------------------------------------------------------------------------
// MFMA bf16 GEMM with strides, split-K, bf16/fp32 out, row/col bias, resid, relu.
// D[m][n] = alpha * sum_k A[m*lda+k] * Bt[n*ldb+k]   (A:[M][K], Bt:[N][K] bf16)
// splits>1: writes fp32 partials (alpha applied) at D + sp*partStride.
__global__ __launch_bounds__(256) void gemm_bt(
    const __hip_bfloat16* __restrict__ A,
    const __hip_bfloat16* __restrict__ Bt,
    float* __restrict__ D,
    __hip_bfloat16* __restrict__ Dbf,
    int M, int N, int K, int lda, int ldb,
    long batchA, long batchB, long batchD,
    int splits, long partStride,
    const float* __restrict__ biasRow,
    const float* __restrict__ biasCol,
    const float* __restrict__ resid, long batchR,
    float alpha, int relu)
{
    __shared__ __align__(16) __hip_bfloat16 As[128 * 32];
    __shared__ __align__(16) __hip_bfloat16 Bs[128 * 32];
    int zz = blockIdx.z;
    int bz = zz / splits, sp = zz % splits;
    const __hip_bfloat16* Ab = A + (long)bz * batchA;
    const __hip_bfloat16* Bb = Bt + (long)bz * batchB;
    int m0 = blockIdx.y * 128, n0 = blockIdx.x * 128;
    int tid = threadIdx.x;
    int lane = tid & 63, wave = tid >> 6;
    int wr = wave >> 1, wc = wave & 1;
    int lr = lane & 15, lg = lane >> 4;
    int kLen = K / splits, kBeg = sp * kLen;

    f32x4 acc[4][4];
    #pragma unroll
    for (int i = 0; i < 4; ++i)
        #pragma unroll
        for (int j = 0; j < 4; ++j)
            #pragma unroll
            for (int r = 0; r < 4; ++r) acc[i][j][r] = 0.f;

    for (int k0 = kBeg; k0 < kBeg + kLen; k0 += 32) {
        #pragma unroll
        for (int q = 0; q < 2; ++q) {
            int idx = q * 256 + tid;
            int row = idx >> 2;
            int ke = (idx & 3) * 8;
            uint4 va = *(const uint4*)(Ab + (long)(m0 + row) * lda + k0 + ke);
            uint4 vb = *(const uint4*)(Bb + (long)(n0 + row) * ldb + k0 + ke);
            ((uint4*)As)[idx] = va;
            ((uint4*)Bs)[idx] = vb;
        }
        __syncthreads();
        bf16x8 af[4], bfr[4];
        #pragma unroll
        for (int i = 0; i < 4; ++i)
            af[i] = *(const bf16x8*)(As + (wr * 64 + i * 16 + lr) * 32 + lg * 8);
        #pragma unroll
        for (int j = 0; j < 4; ++j)
            bfr[j] = *(const bf16x8*)(Bs + (wc * 64 + j * 16 + lr) * 32 + lg * 8);
        #pragma unroll
        for (int i = 0; i < 4; ++i)
            #pragma unroll
            for (int j = 0; j < 4; ++j)
                acc[i][j] = __builtin_amdgcn_mfma_f32_16x16x32_bf16(af[i], bfr[j], acc[i][j], 0, 0, 0);
        __syncthreads();
    }

    if (splits > 1) {
        float* Dp = D + (long)bz * batchD + (long)sp * partStride;
        #pragma unroll
        for (int i = 0; i < 4; ++i)
            #pragma unroll
            for (int r = 0; r < 4; ++r) {
                int row = m0 + wr * 64 + i * 16 + lg * 4 + r;
                #pragma unroll
                for (int j = 0; j < 4; ++j) {
                    int cc = n0 + wc * 64 + lr + j * 16;
                    Dp[(long)row * N + cc] = acc[i][j][r] * alpha;
                }
            }
        return;
    }

    int colc = n0 + wc * 64 + lr;
    #pragma unroll
    for (int i = 0; i < 4; ++i) {
        #pragma unroll
        for (int r = 0; r < 4; ++r) {
            int row = m0 + wr * 64 + i * 16 + lg * 4 + r;
            float brv = biasRow ? biasRow[row] : 0.f;
            #pragma unroll
            for (int j = 0; j < 4; ++j) {
                int cc = colc + j * 16;
                float v = acc[i][j][r] * alpha + brv;
                if (biasCol) v += biasCol[(long)bz * N + cc];
                if (resid) v += resid[(long)bz * batchR + (long)row * N + cc];
                if (relu) v = fmaxf(v, 0.f);
                if (Dbf) Dbf[(long)bz * batchD + (long)row * N + cc] = __float2bfloat16(v);
                else     D[(long)bz * batchD + (long)row * N + cc] = v;
            }
        }
    }
}

// ---------------------------------------------------------------------------
// Sum split-K partials -> bf16 (optional relu). n multiple of 4096.
__global__ __launch_bounds__(256) void reduce_partials(
    const float* __restrict__ part, long partStride, int splits,
    __hip_bfloat16* __restrict__ out, long n, int relu)
{
    long i = ((long)blockIdx.x * 256 + threadIdx.x) * 4;
    if (i >= n) return;
    f32x4 s = *(const f32x4*)(part + i);
    for (int sp = 1; sp < splits; ++sp) {
        f32x4 v = *(const f32x4*)(part + (long)sp * partStride + i);
        s += v;
    }
    union { ushort4 u; __hip_bfloat16 h[4]; } cv;
    #pragma unroll
    for (int k = 0; k < 4; ++k) {
        float v = s[k];
        if (relu) v = fmaxf(v, 0.f);
        cv.h[k] = __float2bfloat16(v);
    }
    *(ushort4*)(out + i) = cv.u;
}

// ---------------------------------------------------------------------------
// v slice of qkvT -> vB [B][C][N] bf16 (LDS transpose)
__global__ __launch_bounds__(256) void extract_v(
    const __hip_bfloat16* __restrict__ qkvT, __hip_bfloat16* __restrict__ vB)
{
    int b = blockIdx.z;
    int c0 = blockIdx.y * 64, m0 = blockIdx.x * 64;
    __shared__ __hip_bfloat16 tb[64][66];
    int tx = threadIdx.x & 63, tg = threadIdx.x >> 6;
    for (int rr = tg; rr < 64; rr += 4)
        tb[rr][tx] = qkvT[((long)b * Nn_ + m0 + rr) * (3 * C) + 2 * C + c0 + tx];
    __syncthreads();
    for (int rr = tg; rr < 64; rr += 4)
        vB[((long)b * C + c0 + rr) * Nn_ + m0 + tx] = tb[tx][rr];
}

// ---------------------------------------------------------------------------
// Row softmax: fp32 in -> bf16 out. grid = 4096, block 256.
__global__ __launch_bounds__(256) void softmax_rows_bf16(
    const float* __restrict__ S, __hip_bfloat16* __restrict__ P)
{
    __shared__ float row[Nn_];
    __shared__ float red[256];
    long r = blockIdx.x;
    const float* p = S + r * (long)Nn_;
    int t = threadIdx.x;
    float mx = -1e30f;
    for (int j = 0; j < Nn_ / 256; ++j) {
        float v = p[j * 256 + t];
        row[j * 256 + t] = v;
        mx = fmaxf(mx, v);
    }
    red[t] = mx; __syncthreads();
    for (int s = 128; s > 0; s >>= 1) {
        if (t < s) red[t] = fmaxf(red[t], red[t + s]);
        __syncthreads();
    }
    mx = red[0]; __syncthreads();
    float sum = 0.f;
    for (int j = 0; j < Nn_ / 256; ++j) {
        float e = __expf(row[j * 256 + t] - mx);
        row[j * 256 + t] = e; sum += e;
    }
    red[t] = sum; __syncthreads();
    for (int s = 128; s > 0; s >>= 1) {
        if (t < s) red[t] += red[t + s];
        __syncthreads();
    }
    float inv = 1.0f / red[0];
    for (int j = 0; j < Nn_ / 256; ++j)
        P[r * (long)Nn_ + j * 256 + t] = __float2bfloat16(row[j * 256 + t] * inv);
}

// ---------------------------------------------------------------------------
__global__ __launch_bounds__(256) void kv_proj_kernel(
    const float* __restrict__ ctx, const float* __restrict__ Wkv,
    const float* __restrict__ bkv, float* __restrict__ kvc)
{
    int b = blockIdx.x / NC, i = blockIdx.x % NC;
    int j = threadIdx.x;
    const float* cv = ctx + ((long)b * NC + i) * C;
    __shared__ float cs[C];
    cs[j] = cv[j];
    __syncthreads();
    float acc = bkv[j];
    for (int cc = 0; cc < C; ++cc) acc += cs[cc] * Wkv[(long)j * C + cc];
    int half = j / HID, h = j % HID;
    kvc[((long)b * 2 + half) * HID * NC + (long)h * NC + i] = acc;
}

// ---------------------------------------------------------------------------
// Cross attention; writes refcT [B][N][HID] bf16 via LDS transpose.
// grid = B*N/128 blocks, 256 threads (threads 0..127 compute one position each).
__global__ __launch_bounds__(256) void cross_attn_kernel(
    const float* __restrict__ qc, const float* __restrict__ kvc,
    __hip_bfloat16* __restrict__ refcT)
{
    int blk = blockIdx.x;
    int b = blk / (Nn_ / 128);
    long n0 = (long)(blk % (Nn_ / 128)) * 128;
    int t = threadIdx.x;
    __shared__ float kl[HID][NC], vl[HID][NC];
    __shared__ __hip_bfloat16 refl[128][HID + 2];
    const float* kb = kvc + (long)b * 2 * HID * NC;
    for (int l = t; l < HID * NC; l += 256) {
        kl[l / NC][l % NC] = kb[l];
        vl[l / NC][l % NC] = kb[HID * NC + l];
    }
    __syncthreads();
    if (t < 128) {
        long n = n0 + t;
        float s[NC];
        #pragma unroll
        for (int m = 0; m < NC; ++m) s[m] = 0.f;
        for (int h = 0; h < HID; ++h) {
            float qh = qc[(long)b * HID * Nn_ + (long)h * Nn_ + n];
            #pragma unroll
            for (int m = 0; m < NC; ++m) s[m] += qh * kl[h][m];
        }
        const float sc = 0.08838834764831845f;   // 1/sqrt(128)
        float mx = -1e30f;
        #pragma unroll
        for (int m = 0; m < NC; ++m) { s[m] *= sc; mx = fmaxf(mx, s[m]); }
        float sum = 0.f;
        #pragma unroll
        for (int m = 0; m < NC; ++m) { s[m] = __expf(s[m] - mx); sum += s[m]; }
        float inv = 1.0f / sum;
        for (int h = 0; h < HID; ++h) {
            float acc = 0.f;
            #pragma unroll
            for (int m = 0; m < NC; ++m) acc += vl[h][m] * s[m];
            refl[t][h] = __float2bfloat16(acc * inv);
        }
    }
    __syncthreads();
    for (int it = 0; it < 64; ++it) {
        int r = it * 2 + (t >> 7);
        int h = t & 127;
        refcT[((long)b * Nn_ + n0 + r) * HID + h] = refl[r][h];
    }
}

// ---------------------------------------------------------------------------
// im2col: col[n][ic*9+tap] bf16 from outself/outcross fp32.
__global__ __launch_bounds__(256) void im2col_kernel(
    const float* __restrict__ os, const float* __restrict__ oc,
    __hip_bfloat16* __restrict__ col)
{
    int n = blockIdx.x;
    int h = n >> 6, w = n & 63;
    for (int k = threadIdx.x; k < 2 * C * 9; k += 256) {
        int ic = k / 9, tap = k % 9;
        int kh = tap / 3, kw = tap % 3;
        int gh = h + kh - 1, gw = w + kw - 1;
        float v = 0.f;
        if ((unsigned)gh < (unsigned)Hh && (unsigned)gw < (unsigned)Ww) {
            const float* src = (ic < C) ? os : oc;
            int ch = ic & (C - 1);
            v = src[(long)ch * Nn_ + gh * Ww + gw];
        }
        col[(long)n * (2 * C * 9) + k] = __float2bfloat16(v);
    }
}

// ---------------------------------------------------------------------------
extern "C" void kernel_launch(void* const* d_in, const int* in_sizes, int n_in,
                              void* d_out, int out_size, void* d_ws, size_t ws_size,
                              hipStream_t stream)
{
    const float* qry   = (const float*)d_in[0];
    const float* arch  = (const float*)d_in[1];
    const float* ctx   = (const float*)d_in[2];
    const float* ln1_g = (const float*)d_in[3];
    const float* ln1_b = (const float*)d_in[4];
    const float* Wqkv  = (const float*)d_in[5];
    const float* bqkv  = (const float*)d_in[6];
    const float* Wproj = (const float*)d_in[7];
    const float* bproj = (const float*)d_in[8];
    const float* Wg    = (const float*)d_in[9];
    const float* bg    = (const float*)d_in[10];
    const float* ln2_g = (const float*)d_in[11];
    const float* ln2_b = (const float*)d_in[12];
    const float* Wq    = (const float*)d_in[13];
    const float* bq    = (const float*)d_in[14];
    const float* Wkv   = (const float*)d_in[15];
    const float* bkv   = (const float*)d_in[16];
    const float* Wout  = (const float*)d_in[17];
    const float* bout  = (const float*)d_in[18];
    const float* Wf1   = (const float*)d_in[19];
    const float* Wf2   = (const float*)d_in[20];
    const float* bf2   = (const float*)d_in[21];
    float* out = (float*)d_out;

    const long CN  = (long)C * Nn_;          // 1,048,576
    const long MN  = (long)Nn_ * C;          // partial tile size (4096x256)
    char* ws = (char*)d_ws;
    size_t off = 0;
    auto alloc = [&](size_t bytes) -> char* {
        char* p = ws + off;
        off += (bytes + 255) & ~size_t(255);
        return p;
    };
    float* S        = (float*)alloc((long)Nn_ * Nn_ * 4);       // 64MB (aliased by colb)
    float* partials = (float*)alloc(8 * MN * 4);                // 32MB
    float* outself  = (float*)alloc(Bb_ * CN * 4);
    float* outcross = (float*)alloc(Bb_ * CN * 4);
    float* qc       = (float*)alloc((long)Bb_ * HID * Nn_ * 4);
    float* kvc      = (float*)alloc((long)Bb_ * 2 * HID * NC * 4);
    float* gate     = (float*)alloc(Bb_ * C * 4);
    float* biasCol  = (float*)alloc((long)Bb_ * 3 * C * 4);
    __hip_bfloat16* x1T    = (__hip_bfloat16*)alloc(Bb_ * MN * 2);
    __hip_bfloat16* x2T    = (__hip_bfloat16*)alloc(Bb_ * MN * 2);
    __hip_bfloat16* qkvT   = (__hip_bfloat16*)alloc((long)Bb_ * Nn_ * 3 * C * 2);
    __hip_bfloat16* vB     = (__hip_bfloat16*)alloc(Bb_ * CN * 2);
    __hip_bfloat16* P      = (__hip_bfloat16*)alloc((long)Nn_ * Nn_ * 2);
    __hip_bfloat16* refsT  = (__hip_bfloat16*)alloc(Bb_ * MN * 2);
    __hip_bfloat16* refcT  = (__hip_bfloat16*)alloc((long)Bb_ * Nn_ * HID * 2);
    __hip_bfloat16* y1T    = (__hip_bfloat16*)alloc(Bb_ * MN * 2);
    __hip_bfloat16* WqkvG  = (__hip_bfloat16*)alloc((long)Bb_ * 3 * C * C * 2);
    __hip_bfloat16* Wprojb = (__hip_bfloat16*)alloc((long)C * C * 2);
    __hip_bfloat16* Wqb    = (__hip_bfloat16*)alloc((long)HID * C * 2);
    __hip_bfloat16* Woutb  = (__hip_bfloat16*)alloc((long)C * HID * 2);
    __hip_bfloat16* Wf1b   = (__hip_bfloat16*)alloc((long)C * 2 * C * 9 * 2);
    __hip_bfloat16* Wf2b   = (__hip_bfloat16*)alloc((long)C * C * 2);
    __hip_bfloat16* colb   = (__hip_bfloat16*)S;   // alias: S dead before conv

    // 1. layernorm -> x1T, x2T bf16 [B][N][C]
    lnT_kernel<<<Bb_ * (Nn_ / 64), 256, 0, stream>>>(qry, ln1_g, ln1_b, ln2_g, ln2_b, x1T, x2T);

    // 2. gate, gated Wqkv + col bias
    gate_kernel<<<Bb_, 256, 0, stream>>>(arch, Wg, bg, gate);
    build_wqkv<<<(Bb_ * 3 * C * C + 255) / 256, 256, 0, stream>>>(Wqkv, bqkv, gate, WqkvG, biasCol);

    // 3. weight casts
    cast_f2b<<<(C * C + 255) / 256, 256, 0, stream>>>(Wproj, Wprojb, (long)C * C);
    cast_f2b<<<(HID * C + 255) / 256, 256, 0, stream>>>(Wq, Wqb, (long)HID * C);
    cast_f2b<<<(C * HID + 255) / 256, 256, 0, stream>>>(Wout, Woutb, (long)C * HID);
    cast_f2b<<<((long)C * 2 * C * 9 + 255) / 256, 256, 0, stream>>>(Wf1, Wf1b, (long)C * 2 * C * 9);
    cast_f2b<<<(C * C + 255) / 256, 256, 0, stream>>>(Wf2, Wf2b, (long)C * C);

    // 4. qkvT = x1T @ WqkvG^T + biasCol  -> bf16 [B][N][768]
    gemm_bt<<<dim3(3 * C / 128, Nn_ / 128, Bb_), 256, 0, stream>>>(
        x1T, WqkvG, nullptr, qkvT, Nn_, 3 * C, C, C, C,
        MN, (long)3 * C * C, (long)Nn_ * 3 * C,
        1, 0, nullptr, biasCol, nullptr, 0, 1.0f, 0);

    // 5. v -> vB [B][C][N]
    extract_v<<<dim3(Nn_ / 64, C / 64, Bb_), 256, 0, stream>>>(qkvT, vB);

    // 6. self attention per batch
    for (int b = 0; b < Bb_; ++b) {
        const __hip_bfloat16* qkb = qkvT + (long)b * Nn_ * 3 * C;
        // scores S[n][m] = (1/16) q[n]·k_g[m]
        gemm_bt<<<dim3(Nn_ / 128, Nn_ / 128, 1), 256, 0, stream>>>(
            qkb, qkb + C, S, nullptr, Nn_, Nn_, C, 3 * C, 3 * C,
            0, 0, 0, 1, 0, nullptr, nullptr, nullptr, 0, 0.0625f, 0);
        softmax_rows_bf16<<<Nn_, 256, 0, stream>>>(S, P);
        // PV split-K: refsT[n][c] = sum_m P[n][m] vB[c][m]
        gemm_bt<<<dim3(C / 128, Nn_ / 128, 8), 256, 0, stream>>>(
            P, vB + (long)b * CN, partials, nullptr, Nn_, C, Nn_, Nn_, Nn_,
            0, 0, 0, 8, MN, nullptr, nullptr, nullptr, 0, 1.0f, 0);
        reduce_partials<<<(int)(MN / 1024), 256, 0, stream>>>(
            partials, MN, 8, refsT + (long)b * MN, MN, 0);
    }

    // 7. outself = qry + Wproj @ refs + bproj   (fp32 [B][C][N])
    gemm_bt<<<dim3(Nn_ / 128, C / 128, Bb_), 256, 0, stream>>>(
        Wprojb, refsT, outself, nullptr, C, Nn_, C, C, C,
        0, MN, CN, 1, 0, bproj, nullptr, qry, CN, 1.0f, 0);

    // 8. qc = Wq @ x2 + bq   (fp32 [B][HID][N])
    gemm_bt<<<dim3(Nn_ / 128, HID / 128, Bb_), 256, 0, stream>>>(
        Wqb, x2T, qc, nullptr, HID, Nn_, C, C, C,
        0, MN, (long)HID * Nn_, 1, 0, bq, nullptr, nullptr, 0, 1.0f, 0);

    // 9. cross attention
    kv_proj_kernel<<<Bb_ * NC, 256, 0, stream>>>(ctx, Wkv, bkv, kvc);
    cross_attn_kernel<<<Bb_ * (Nn_ / 128), 256, 0, stream>>>(qc, kvc, refcT);

    // 10. outcross = qry + Wout @ refc + bout
    gemm_bt<<<dim3(Nn_ / 128, C / 128, Bb_), 256, 0, stream>>>(
        Woutb, refcT, outcross, nullptr, C, Nn_, HID, HID, HID,
        0, (long)Nn_ * HID, CN, 1, 0, bout, nullptr, qry, CN, 1.0f, 0);

    // 11. conv3x3 + ReLU: im2col then split-K GEMM -> y1T bf16 [N][C]
    for (int b = 0; b < Bb_; ++b) {
        im2col_kernel<<<Nn_, 256, 0, stream>>>(
            outself + (long)b * CN, outcross + (long)b * CN, colb);
        gemm_bt<<<dim3(C / 128, Nn_ / 128, 8), 256, 0, stream>>>(
            colb, Wf1b, partials, nullptr, Nn_, C, 2 * C * 9, 2 * C * 9, 2 * C * 9,
            0, 0, 0, 8, MN, nullptr, nullptr, nullptr, 0, 1.0f, 0);
        reduce_partials<<<(int)(MN / 1024), 256, 0, stream>>>(
            partials, MN, 8, y1T + (long)b * MN, MN, 1);
    }

    // 12. out = qry + Wf2 @ y1 + bf2
    gemm_bt<<<dim3(Nn_ / 128, C / 128, Bb_), 256, 0, stream>>>(
        Wf2b, y1T, out, nullptr, C, Nn_, C, C, C,
        0, MN, CN, 1, 0, bf2, nullptr, qry, CN, 1.0f, 0);
}

// Round 4
// 396.249 us; speedup vs baseline: 8.1216x; 1.2029x over previous
//
#include <hip/hip_runtime.h>
#include <hip/hip_bf16.h>

#define C 256
#define HID 128
#define Bb_ 2
#define Hh 64
#define Ww 64
#define Nn_ 4096
#define NP 16
#define NC 16
#define KVSPLIT 2

typedef __bf16 bf16x8 __attribute__((ext_vector_type(8)));
typedef float f32x4 __attribute__((ext_vector_type(4)));

// ---------------------------------------------------------------------------
// Coalesced tiled LayerNorm -> x1T, x2T bf16 [B][N][C]
__global__ __launch_bounds__(256) void lnT_kernel(
    const float* __restrict__ x,
    const float* __restrict__ g1, const float* __restrict__ b1,
    const float* __restrict__ g2, const float* __restrict__ b2,
    __hip_bfloat16* __restrict__ x1T, __hip_bfloat16* __restrict__ x2T)
{
    int blk = blockIdx.x;
    int b = blk >> 6;
    int n0 = (blk & 63) << 6;
    int t = threadIdx.x;
    __shared__ __hip_bfloat16 xs[64][258];
    __shared__ float rs4[4][64], rq4[4][64], mean[64], inv[64];
    int j = t & 63, cg = t >> 6;
    float s = 0.f, q = 0.f;
    for (int it = 0; it < 64; ++it) {
        int c = it * 4 + cg;
        float v = x[((long)b * C + c) * Nn_ + n0 + j];
        xs[j][c] = __float2bfloat16(v);
        s += v; q += v * v;
    }
    rs4[cg][j] = s; rq4[cg][j] = q;
    __syncthreads();
    if (t < 64) {
        float S = rs4[0][t] + rs4[1][t] + rs4[2][t] + rs4[3][t];
        float Q = rq4[0][t] + rq4[1][t] + rq4[2][t] + rq4[3][t];
        float m = S * (1.0f / C);
        float var = Q * (1.0f / C) - m * m;
        mean[t] = m; inv[t] = rsqrtf(var + 1e-5f);
    }
    __syncthreads();
    float G1 = g1[t], B1 = b1[t], G2 = g2[t], B2 = b2[t];
    for (int j2 = 0; j2 < 64; ++j2) {
        float v = __bfloat162float(xs[j2][t]);
        float xn = (v - mean[j2]) * inv[j2];
        long o = ((long)b * Nn_ + n0 + j2) * C + t;
        x1T[o] = __float2bfloat16(xn * G1 + B1);
        x2T[o] = __float2bfloat16(xn * G2 + B2);
    }
}

// ---------------------------------------------------------------------------
// qry [B][C][N] fp32 -> qryT [B][N][C] fp32 (64x64 LDS tiles)
__global__ __launch_bounds__(256) void transpose_qry(
    const float* __restrict__ qry, float* __restrict__ qryT)
{
    int b = blockIdx.z;
    int c0 = blockIdx.y * 64, n0 = blockIdx.x * 64;
    __shared__ float tf[64][65];
    int tx = threadIdx.x & 63, tg = threadIdx.x >> 6;
    for (int rr = tg; rr < 64; rr += 4)
        tf[rr][tx] = qry[((long)b * C + c0 + rr) * Nn_ + n0 + tx];
    __syncthreads();
    for (int rr = tg; rr < 64; rr += 4)
        qryT[((long)b * Nn_ + n0 + rr) * C + c0 + tx] = tf[tx][rr];
}

// ---------------------------------------------------------------------------
__global__ __launch_bounds__(256) void gate_kernel(
    const float* __restrict__ arch, const float* __restrict__ Wg,
    const float* __restrict__ bg, float* __restrict__ gate)
{
    int b = blockIdx.x;
    int o = threadIdx.x;
    __shared__ float guide[C];
    float s = 0.f;
    for (int p = 0; p < NP; ++p) s += arch[(long)b * NP * C + (long)p * C + o];
    guide[o] = s * (1.0f / NP);
    __syncthreads();
    float acc = bg[o];
    for (int cc = 0; cc < C; ++cc) acc += guide[cc] * Wg[(long)o * C + cc];
    gate[b * C + o] = 1.0f / (1.0f + __expf(-acc));
}

// ---------------------------------------------------------------------------
__global__ __launch_bounds__(256) void build_wqkv(
    const float* __restrict__ Wqkv, const float* __restrict__ bqkv,
    const float* __restrict__ gate,
    __hip_bfloat16* __restrict__ WqkvG, float* __restrict__ biasCol)
{
    long i = (long)blockIdx.x * 256 + threadIdx.x;
    long total = (long)Bb_ * 3 * C * C;
    if (i < total) {
        long b = i / (3 * C * C);
        long rem = i % (3 * C * C);
        int o = (int)(rem / C);
        float v = Wqkv[rem];
        if (o >= C && o < 2 * C) v *= gate[b * C + (o - C)];
        WqkvG[i] = __float2bfloat16(v);
    }
    if (i < (long)Bb_ * 3 * C) {
        long b = i / (3 * C);
        int o = (int)(i % (3 * C));
        float v = bqkv[o];
        if (o >= C && o < 2 * C) v *= gate[b * C + (o - C)];
        biasCol[i] = v;
    }
}

// ---------------------------------------------------------------------------
__global__ __launch_bounds__(256) void cast_f2b(
    const float* __restrict__ in, __hip_bfloat16* __restrict__ out, long n)
{
    long i = (long)blockIdx.x * 256 + threadIdx.x;
    if (i < n) out[i] = __float2bfloat16(in[i]);
}

// ---------------------------------------------------------------------------
// Wf1 [O][512][3][3] -> Wtap [9][O][512] bf16
__global__ __launch_bounds__(256) void build_wtap(
    const float* __restrict__ Wf1, __hip_bfloat16* __restrict__ Wtap)
{
    long i = (long)blockIdx.x * 256 + threadIdx.x;
    if (i >= 9l * C * 2 * C) return;
    int tap = (int)(i / (C * 2 * C));
    long rem = i % (C * 2 * C);
    int o = (int)(rem / (2 * C)), ic = (int)(rem % (2 * C));
    Wtap[i] = __float2bfloat16(Wf1[((long)o * 2 * C + ic) * 9 + tap]);
}

// ---------------------------------------------------------------------------
// MFMA bf16 GEMM: D[m][n] = alpha * sum_k A[m*lda+k]*Bt[n*ldb+k] (+biasRow[m])
//                 (+biasCol[n]) (+resid[m*ldr+n]) (relu), out fp32 or bf16.
// 128x128 tile, BK=32. M,N multiples of 128; K multiple of 32.
__global__ __launch_bounds__(256) void gemm_bt(
    const __hip_bfloat16* __restrict__ A,
    const __hip_bfloat16* __restrict__ Bt,
    float* __restrict__ D,
    __hip_bfloat16* __restrict__ Dbf,
    int M, int N, int K, int lda, int ldb, int ldd,
    long batchA, long batchB, long batchD,
    const float* __restrict__ biasRow,
    const float* __restrict__ biasCol, long bcStride,
    const float* __restrict__ resid, int ldr, long batchR,
    float alpha, int relu)
{
    __shared__ __align__(16) __hip_bfloat16 As[128 * 32];
    __shared__ __align__(16) __hip_bfloat16 Bs[128 * 32];
    int bz = blockIdx.z;
    const __hip_bfloat16* Ab = A + (long)bz * batchA;
    const __hip_bfloat16* Bb = Bt + (long)bz * batchB;
    int m0 = blockIdx.y * 128, n0 = blockIdx.x * 128;
    int tid = threadIdx.x;
    int lane = tid & 63, wave = tid >> 6;
    int wr = wave >> 1, wc = wave & 1;
    int lr = lane & 15, lg = lane >> 4;

    f32x4 acc[4][4];
    #pragma unroll
    for (int i = 0; i < 4; ++i)
        #pragma unroll
        for (int j = 0; j < 4; ++j)
            #pragma unroll
            for (int r = 0; r < 4; ++r) acc[i][j][r] = 0.f;

    for (int k0 = 0; k0 < K; k0 += 32) {
        #pragma unroll
        for (int q = 0; q < 2; ++q) {
            int idx = q * 256 + tid;
            int row = idx >> 2;
            int ke = (idx & 3) * 8;
            uint4 va = *(const uint4*)(Ab + (long)(m0 + row) * lda + k0 + ke);
            uint4 vb = *(const uint4*)(Bb + (long)(n0 + row) * ldb + k0 + ke);
            ((uint4*)As)[idx] = va;
            ((uint4*)Bs)[idx] = vb;
        }
        __syncthreads();
        bf16x8 af[4], bfr[4];
        #pragma unroll
        for (int i = 0; i < 4; ++i)
            af[i] = *(const bf16x8*)(As + (wr * 64 + i * 16 + lr) * 32 + lg * 8);
        #pragma unroll
        for (int j = 0; j < 4; ++j)
            bfr[j] = *(const bf16x8*)(Bs + (wc * 64 + j * 16 + lr) * 32 + lg * 8);
        #pragma unroll
        for (int i = 0; i < 4; ++i)
            #pragma unroll
            for (int j = 0; j < 4; ++j)
                acc[i][j] = __builtin_amdgcn_mfma_f32_16x16x32_bf16(af[i], bfr[j], acc[i][j], 0, 0, 0);
        __syncthreads();
    }

    int colc = n0 + wc * 64 + lr;
    #pragma unroll
    for (int i = 0; i < 4; ++i) {
        #pragma unroll
        for (int r = 0; r < 4; ++r) {
            int row = m0 + wr * 64 + i * 16 + lg * 4 + r;
            float brv = biasRow ? biasRow[row] : 0.f;
            #pragma unroll
            for (int j = 0; j < 4; ++j) {
                int cc = colc + j * 16;
                float v = acc[i][j][r] * alpha + brv;
                if (biasCol) v += biasCol[bz * bcStride + cc];
                if (resid) v += resid[(long)bz * batchR + (long)row * ldr + cc];
                if (relu) v = fmaxf(v, 0.f);
                long oa = (long)bz * batchD + (long)row * ldd + cc;
                if (Dbf) Dbf[oa] = __float2bfloat16(v);
                else     D[oa] = v;
            }
        }
    }
}

// ---------------------------------------------------------------------------
// v slice of qkvT -> vB [B][C][N] bf16
__global__ __launch_bounds__(256) void extract_v(
    const __hip_bfloat16* __restrict__ qkvT, __hip_bfloat16* __restrict__ vB)
{
    int b = blockIdx.z;
    int c0 = blockIdx.y * 64, m0 = blockIdx.x * 64;
    __shared__ __hip_bfloat16 tb[64][66];
    int tx = threadIdx.x & 63, tg = threadIdx.x >> 6;
    for (int rr = tg; rr < 64; rr += 4)
        tb[rr][tx] = qkvT[((long)b * Nn_ + m0 + rr) * (3 * C) + 2 * C + c0 + tx];
    __syncthreads();
    for (int rr = tg; rr < 64; rr += 4)
        vB[((long)b * C + c0 + rr) * Nn_ + m0 + tx] = tb[tx][rr];
}

// ---------------------------------------------------------------------------
// Flash attention: S = (1/16) q.k_g, online softmax, O = P.V (unnormalized).
// grid (64 Qtiles, KVSPLIT, B), 256 threads (4 waves x 16 Q-rows).
// Q from qkvT[n][0..256), K from qkvT[n][256..512) (gate folded), V from vB.
__global__ __launch_bounds__(256) void flash_attn(
    const __hip_bfloat16* __restrict__ qkvT,
    const __hip_bfloat16* __restrict__ vB,
    float* __restrict__ Opart,      // [B][KVSPLIT][N][256]
    float* __restrict__ ml)         // [B][KVSPLIT][N][2]
{
    int qb = blockIdx.x, sp = blockIdx.y, b = blockIdx.z;
    int n0 = qb * 64;
    int tid = threadIdx.x;
    int lane = tid & 63, w = tid >> 6;
    int lr = lane & 15, lg = lane >> 4;

    __shared__ __align__(16) __hip_bfloat16 KV[256 * 72];    // K:[64][264] / Vt:[256][72]
    __shared__ __align__(16) __hip_bfloat16 Pl[64 * 72];

    // Q fragments in registers (wave w owns q-rows n0 + w*16 + lr)
    bf16x8 qf[8];
    {
        const __hip_bfloat16* qp = qkvT + ((long)b * Nn_ + n0 + w * 16 + lr) * (3 * C);
        #pragma unroll
        for (int ks = 0; ks < 8; ++ks)
            qf[ks] = *(const bf16x8*)(qp + ks * 32 + lg * 8);
    }

    f32x4 Oacc[16];
    #pragma unroll
    for (int jd = 0; jd < 16; ++jd)
        #pragma unroll
        for (int r = 0; r < 4; ++r) Oacc[jd][r] = 0.f;
    float m_r[4], l_r[4];
    #pragma unroll
    for (int r = 0; r < 4; ++r) { m_r[r] = -1e30f; l_r[r] = 0.f; }

    const float sc = 0.0625f;
    int kvBeg = sp * (Nn_ / KVSPLIT);
    for (int t = 0; t < (Nn_ / KVSPLIT) / 64; ++t) {
        int kv0 = kvBeg + t * 64;
        // ---- stage K tile [64][264] from qkvT rows kv0.., cols C..2C
        {
            const __hip_bfloat16* kp = qkvT + ((long)b * Nn_ + kv0) * (3 * C) + C;
            #pragma unroll
            for (int ps = 0; ps < 8; ++ps) {
                int idx = ps * 256 + tid;
                int row = idx >> 5, c8 = idx & 31;
                *(uint4*)(&KV[row * 264 + c8 * 8]) =
                    *(const uint4*)(kp + (long)row * (3 * C) + c8 * 8);
            }
        }
        __syncthreads();
        // ---- S = Q K^T (per wave: 16 rows x 64 cols)
        f32x4 sacc[4];
        #pragma unroll
        for (int j = 0; j < 4; ++j)
            #pragma unroll
            for (int r = 0; r < 4; ++r) sacc[j][r] = 0.f;
        #pragma unroll
        for (int ks = 0; ks < 8; ++ks) {
            #pragma unroll
            for (int j = 0; j < 4; ++j) {
                bf16x8 kf = *(const bf16x8*)(&KV[(j * 16 + lr) * 264 + ks * 32 + lg * 8]);
                sacc[j] = __builtin_amdgcn_mfma_f32_16x16x32_bf16(qf[ks], kf, sacc[j], 0, 0, 0);
            }
        }
        // ---- online softmax (rows 4*lg + r within wave tile)
        float scale_old[4], ls[4];
        #pragma unroll
        for (int r = 0; r < 4; ++r) {
            float v = fmaxf(fmaxf(sacc[0][r], sacc[1][r]),
                            fmaxf(sacc[2][r], sacc[3][r])) * sc;
            #pragma unroll
            for (int off = 1; off <= 8; off <<= 1)
                v = fmaxf(v, __shfl_xor(v, off));
            float mnew = fmaxf(m_r[r], v);
            scale_old[r] = __expf(m_r[r] - mnew);
            m_r[r] = mnew;
            ls[r] = 0.f;
        }
        #pragma unroll
        for (int j = 0; j < 4; ++j)
            #pragma unroll
            for (int r = 0; r < 4; ++r) {
                float p = __expf(sacc[j][r] * sc - m_r[r]);
                ls[r] += p;
                Pl[(w * 16 + 4 * lg + r) * 72 + j * 16 + lr] = __float2bfloat16(p);
            }
        #pragma unroll
        for (int r = 0; r < 4; ++r) {
            float v = ls[r];
            #pragma unroll
            for (int off = 1; off <= 8; off <<= 1)
                v += __shfl_xor(v, off);
            l_r[r] = l_r[r] * scale_old[r] + v;
        }
        #pragma unroll
        for (int jd = 0; jd < 16; ++jd)
            #pragma unroll
            for (int r = 0; r < 4; ++r) Oacc[jd][r] *= scale_old[r];
        __syncthreads();   // all waves done reading K
        // ---- stage Vt tile [256][72] from vB rows d, cols kv0..kv0+63
        {
            const __hip_bfloat16* vp = vB + (long)b * C * Nn_ + kv0;
            #pragma unroll
            for (int ps = 0; ps < 8; ++ps) {
                int idx = ps * 256 + tid;
                int row = idx >> 3, c8 = idx & 7;
                *(uint4*)(&KV[row * 72 + c8 * 8]) =
                    *(const uint4*)(vp + (long)row * Nn_ + c8 * 8);
            }
        }
        __syncthreads();
        // ---- O += P V^T
        #pragma unroll
        for (int ks = 0; ks < 2; ++ks) {
            bf16x8 pf = *(const bf16x8*)(&Pl[(w * 16 + lr) * 72 + ks * 32 + lg * 8]);
            #pragma unroll
            for (int jd = 0; jd < 16; ++jd) {
                bf16x8 vf = *(const bf16x8*)(&KV[(jd * 16 + lr) * 72 + ks * 32 + lg * 8]);
                Oacc[jd] = __builtin_amdgcn_mfma_f32_16x16x32_bf16(pf, vf, Oacc[jd], 0, 0, 0);
            }
        }
        __syncthreads();   // before next K staging overwrites Vt
    }

    float* Op = Opart + (((long)b * KVSPLIT + sp) * Nn_ + n0) * 256;
    #pragma unroll
    for (int jd = 0; jd < 16; ++jd)
        #pragma unroll
        for (int r = 0; r < 4; ++r) {
            int row = w * 16 + lg * 4 + r;
            Op[(long)row * 256 + jd * 16 + lr] = Oacc[jd][r];
        }
    if (lr == 0) {
        float* mlp = ml + (((long)b * KVSPLIT + sp) * Nn_ + n0) * 2;
        #pragma unroll
        for (int r = 0; r < 4; ++r) {
            int row = w * 16 + lg * 4 + r;
            mlp[row * 2] = m_r[r];
            mlp[row * 2 + 1] = l_r[r];
        }
    }
}

// ---------------------------------------------------------------------------
// Merge KVSPLIT partials -> refsT bf16 [B][N][256]
__global__ __launch_bounds__(256) void merge_flash(
    const float* __restrict__ Opart, const float* __restrict__ ml,
    __hip_bfloat16* __restrict__ refsT)
{
    long gi = (long)blockIdx.x * 256 + threadIdx.x;
    long row = gi >> 6;              // over B*N
    int c4 = (int)(gi & 63) * 4;
    long b = row / Nn_, n = row % Nn_;
    long r0 = ((b * KVSPLIT + 0) * Nn_ + n);
    long r1 = ((b * KVSPLIT + 1) * Nn_ + n);
    float m0 = ml[r0 * 2], l0 = ml[r0 * 2 + 1];
    float m1 = ml[r1 * 2], l1 = ml[r1 * 2 + 1];
    float m = fmaxf(m0, m1);
    float a0 = __expf(m0 - m), a1 = __expf(m1 - m);
    float dn = 1.0f / (l0 * a0 + l1 * a1);
    f32x4 o0 = *(const f32x4*)(Opart + r0 * 256 + c4);
    f32x4 o1 = *(const f32x4*)(Opart + r1 * 256 + c4);
    union { ushort4 u; __hip_bfloat16 h[4]; } cv;
    #pragma unroll
    for (int k = 0; k < 4; ++k)
        cv.h[k] = __float2bfloat16((o0[k] * a0 + o1[k] * a1) * dn);
    *(ushort4*)(refsT + (b * Nn_ + n) * 256 + c4) = cv.u;
}

// ---------------------------------------------------------------------------
// Implicit-GEMM 3x3 conv, tap-split (kh) into 3 partial accumulations.
// grid (2, 32, B*3). partials [B][3][N][256] fp32.
__global__ __launch_bounds__(256) void conv3x3_gemm(
    const __hip_bfloat16* __restrict__ catT,   // [B][N][512]
    const __hip_bfloat16* __restrict__ Wtap,   // [9][256][512]
    float* __restrict__ partials)
{
    __shared__ __align__(16) __hip_bfloat16 As[128 * 32];
    __shared__ __align__(16) __hip_bfloat16 Bs[128 * 32];
    int z = blockIdx.z;
    int b = z / 3, sp = z % 3;
    int dh = sp - 1;
    int o0 = blockIdx.x * 128, m0 = blockIdx.y * 128;
    int tid = threadIdx.x;
    int lane = tid & 63, wave = tid >> 6;
    int wr = wave >> 1, wc = wave & 1;
    int lr = lane & 15, lg = lane >> 4;
    const __hip_bfloat16* cb = catT + (long)b * Nn_ * (2 * C);

    f32x4 acc[4][4];
    #pragma unroll
    for (int i = 0; i < 4; ++i)
        #pragma unroll
        for (int j = 0; j < 4; ++j)
            #pragma unroll
            for (int r = 0; r < 4; ++r) acc[i][j][r] = 0.f;

    for (int kw = 0; kw < 3; ++kw) {
        int dw = kw - 1;
        const __hip_bfloat16* wt = Wtap + (long)(sp * 3 + kw) * C * (2 * C);
        for (int k0 = 0; k0 < 2 * C; k0 += 32) {
            #pragma unroll
            for (int q = 0; q < 2; ++q) {
                int idx = q * 256 + tid;
                int row = idx >> 2;
                int ke = (idx & 3) * 8;
                int gm = m0 + row;
                int h = (gm >> 6) + dh, w2 = (gm & 63) + dw;
                uint4 va = {0, 0, 0, 0};
                if ((unsigned)h < 64u && (unsigned)w2 < 64u)
                    va = *(const uint4*)(cb + ((long)((h << 6) + w2)) * (2 * C) + k0 + ke);
                ((uint4*)As)[idx] = va;
                ((uint4*)Bs)[idx] = *(const uint4*)(wt + (long)(o0 + row) * (2 * C) + k0 + ke);
            }
            __syncthreads();
            bf16x8 af[4], bfr[4];
            #pragma unroll
            for (int i = 0; i < 4; ++i)
                af[i] = *(const bf16x8*)(As + (wr * 64 + i * 16 + lr) * 32 + lg * 8);
            #pragma unroll
            for (int j = 0; j < 4; ++j)
                bfr[j] = *(const bf16x8*)(Bs + (wc * 64 + j * 16 + lr) * 32 + lg * 8);
            #pragma unroll
            for (int i = 0; i < 4; ++i)
                #pragma unroll
                for (int j = 0; j < 4; ++j)
                    acc[i][j] = __builtin_amdgcn_mfma_f32_16x16x32_bf16(af[i], bfr[j], acc[i][j], 0, 0, 0);
            __syncthreads();
        }
    }

    float* Dp = partials + ((long)(b * 3 + sp) * Nn_ + m0) * 256;
    #pragma unroll
    for (int i = 0; i < 4; ++i)
        #pragma unroll
        for (int r = 0; r < 4; ++r) {
            int row = wr * 64 + i * 16 + lg * 4 + r;
            #pragma unroll
            for (int j = 0; j < 4; ++j)
                Dp[(long)row * 256 + o0 + wc * 64 + j * 16 + lr] = acc[i][j][r];
        }
}

// ---------------------------------------------------------------------------
__global__ __launch_bounds__(256) void reduce_partials(
    const float* __restrict__ part, long partStride, int splits,
    __hip_bfloat16* __restrict__ out, long n, int relu)
{
    long i = ((long)blockIdx.x * 256 + threadIdx.x) * 4;
    if (i >= n) return;
    f32x4 s = *(const f32x4*)(part + i);
    for (int sp = 1; sp < splits; ++sp)
        s += *(const f32x4*)(part + (long)sp * partStride + i);
    union { ushort4 u; __hip_bfloat16 h[4]; } cv;
    #pragma unroll
    for (int k = 0; k < 4; ++k) {
        float v = s[k];
        if (relu) v = fmaxf(v, 0.f);
        cv.h[k] = __float2bfloat16(v);
    }
    *(ushort4*)(out + i) = cv.u;
}

// ---------------------------------------------------------------------------
__global__ __launch_bounds__(256) void kv_proj_kernel(
    const float* __restrict__ ctx, const float* __restrict__ Wkv,
    const float* __restrict__ bkv, float* __restrict__ kvc)
{
    int b = blockIdx.x / NC, i = blockIdx.x % NC;
    int j = threadIdx.x;
    const float* cv = ctx + ((long)b * NC + i) * C;
    __shared__ float cs[C];
    cs[j] = cv[j];
    __syncthreads();
    float acc = bkv[j];
    for (int cc = 0; cc < C; ++cc) acc += cs[cc] * Wkv[(long)j * C + cc];
    int half = j / HID, h = j % HID;
    kvc[((long)b * 2 + half) * HID * NC + (long)h * NC + i] = acc;
}

// ---------------------------------------------------------------------------
__global__ __launch_bounds__(256) void cross_attn_kernel(
    const float* __restrict__ qc, const float* __restrict__ kvc,
    __hip_bfloat16* __restrict__ refcT)
{
    int blk = blockIdx.x;
    int b = blk / (Nn_ / 128);
    long n0 = (long)(blk % (Nn_ / 128)) * 128;
    int t = threadIdx.x;
    __shared__ float kl[HID][NC], vl[HID][NC];
    __shared__ __hip_bfloat16 refl[128][HID + 2];
    const float* kb = kvc + (long)b * 2 * HID * NC;
    for (int l = t; l < HID * NC; l += 256) {
        kl[l / NC][l % NC] = kb[l];
        vl[l / NC][l % NC] = kb[HID * NC + l];
    }
    __syncthreads();
    if (t < 128) {
        long n = n0 + t;
        float s[NC];
        #pragma unroll
        for (int m = 0; m < NC; ++m) s[m] = 0.f;
        for (int h = 0; h < HID; ++h) {
            float qh = qc[(long)b * HID * Nn_ + (long)h * Nn_ + n];
            #pragma unroll
            for (int m = 0; m < NC; ++m) s[m] += qh * kl[h][m];
        }
        const float scc = 0.08838834764831845f;
        float mx = -1e30f;
        #pragma unroll
        for (int m = 0; m < NC; ++m) { s[m] *= scc; mx = fmaxf(mx, s[m]); }
        float sum = 0.f;
        #pragma unroll
        for (int m = 0; m < NC; ++m) { s[m] = __expf(s[m] - mx); sum += s[m]; }
        float inv = 1.0f / sum;
        for (int h = 0; h < HID; ++h) {
            float acc = 0.f;
            #pragma unroll
            for (int m = 0; m < NC; ++m) acc += vl[h][m] * s[m];
            refl[t][h] = __float2bfloat16(acc * inv);
        }
    }
    __syncthreads();
    for (int it = 0; it < 64; ++it) {
        int r = it * 2 + (t >> 7);
        int h = t & 127;
        refcT[((long)b * Nn_ + n0 + r) * HID + h] = refl[r][h];
    }
}

// ---------------------------------------------------------------------------
extern "C" void kernel_launch(void* const* d_in, const int* in_sizes, int n_in,
                              void* d_out, int out_size, void* d_ws, size_t ws_size,
                              hipStream_t stream)
{
    const float* qry   = (const float*)d_in[0];
    const float* arch  = (const float*)d_in[1];
    const float* ctx   = (const float*)d_in[2];
    const float* ln1_g = (const float*)d_in[3];
    const float* ln1_b = (const float*)d_in[4];
    const float* Wqkv  = (const float*)d_in[5];
    const float* bqkv  = (const float*)d_in[6];
    const float* Wproj = (const float*)d_in[7];
    const float* bproj = (const float*)d_in[8];
    const float* Wg    = (const float*)d_in[9];
    const float* bg    = (const float*)d_in[10];
    const float* ln2_g = (const float*)d_in[11];
    const float* ln2_b = (const float*)d_in[12];
    const float* Wq    = (const float*)d_in[13];
    const float* bq    = (const float*)d_in[14];
    const float* Wkv   = (const float*)d_in[15];
    const float* bkv   = (const float*)d_in[16];
    const float* Wout  = (const float*)d_in[17];
    const float* bout  = (const float*)d_in[18];
    const float* Wf1   = (const float*)d_in[19];
    const float* Wf2   = (const float*)d_in[20];
    const float* bf2   = (const float*)d_in[21];
    float* out = (float*)d_out;

    const long CN = (long)C * Nn_;
    const long MN = (long)Nn_ * C;
    char* ws = (char*)d_ws;
    size_t off = 0;
    auto alloc = [&](size_t bytes) -> char* {
        char* p = ws + off;
        off += (bytes + 255) & ~size_t(255);
        return p;
    };
    float* qryT     = (float*)alloc(Bb_ * MN * 4);                       // 8MB
    float* Opart    = (float*)alloc((long)Bb_ * KVSPLIT * MN * 4);       // 16MB
    float* mlbuf    = (float*)alloc((long)Bb_ * KVSPLIT * Nn_ * 2 * 4);
    float* convPart = (float*)alloc((long)Bb_ * 3 * MN * 4);             // 24MB
    float* qc       = (float*)alloc((long)Bb_ * HID * Nn_ * 4);
    float* kvc      = (float*)alloc((long)Bb_ * 2 * HID * NC * 4);
    float* gate     = (float*)alloc(Bb_ * C * 4);
    float* biasCol  = (float*)alloc((long)Bb_ * 3 * C * 4);
    __hip_bfloat16* x1T   = (__hip_bfloat16*)alloc(Bb_ * MN * 2);
    __hip_bfloat16* x2T   = (__hip_bfloat16*)alloc(Bb_ * MN * 2);
    __hip_bfloat16* qkvT  = (__hip_bfloat16*)alloc((long)Bb_ * Nn_ * 3 * C * 2);
    __hip_bfloat16* vB    = (__hip_bfloat16*)alloc(Bb_ * CN * 2);
    __hip_bfloat16* refsT = (__hip_bfloat16*)alloc(Bb_ * MN * 2);
    __hip_bfloat16* refcT = (__hip_bfloat16*)alloc((long)Bb_ * Nn_ * HID * 2);
    __hip_bfloat16* catT  = (__hip_bfloat16*)alloc((long)Bb_ * Nn_ * 2 * C * 2);
    __hip_bfloat16* y1T   = (__hip_bfloat16*)alloc(Bb_ * MN * 2);
    __hip_bfloat16* WqkvG = (__hip_bfloat16*)alloc((long)Bb_ * 3 * C * C * 2);
    __hip_bfloat16* Wprojb= (__hip_bfloat16*)alloc((long)C * C * 2);
    __hip_bfloat16* Wqb   = (__hip_bfloat16*)alloc((long)HID * C * 2);
    __hip_bfloat16* Woutb = (__hip_bfloat16*)alloc((long)C * HID * 2);
    __hip_bfloat16* Wtap  = (__hip_bfloat16*)alloc((long)9 * C * 2 * C * 2);
    __hip_bfloat16* Wf2b  = (__hip_bfloat16*)alloc((long)C * C * 2);

    // 1. layernorm + qry transpose
    lnT_kernel<<<Bb_ * (Nn_ / 64), 256, 0, stream>>>(qry, ln1_g, ln1_b, ln2_g, ln2_b, x1T, x2T);
    transpose_qry<<<dim3(Nn_ / 64, C / 64, Bb_), 256, 0, stream>>>(qry, qryT);

    // 2. gate + weight prep
    gate_kernel<<<Bb_, 256, 0, stream>>>(arch, Wg, bg, gate);
    build_wqkv<<<(Bb_ * 3 * C * C + 255) / 256, 256, 0, stream>>>(Wqkv, bqkv, gate, WqkvG, biasCol);
    cast_f2b<<<(C * C + 255) / 256, 256, 0, stream>>>(Wproj, Wprojb, (long)C * C);
    cast_f2b<<<(HID * C + 255) / 256, 256, 0, stream>>>(Wq, Wqb, (long)HID * C);
    cast_f2b<<<(C * HID + 255) / 256, 256, 0, stream>>>(Wout, Woutb, (long)C * HID);
    cast_f2b<<<(C * C + 255) / 256, 256, 0, stream>>>(Wf2, Wf2b, (long)C * C);
    build_wtap<<<((long)9 * C * 2 * C + 255) / 256, 256, 0, stream>>>(Wf1, Wtap);

    // 3. qkvT = x1T @ WqkvG^T + biasCol  -> bf16 [B][N][768]
    gemm_bt<<<dim3(6, 32, Bb_), 256, 0, stream>>>(
        x1T, WqkvG, nullptr, qkvT, Nn_, 3 * C, C, C, C, 3 * C,
        MN, (long)3 * C * C, (long)Nn_ * 3 * C,
        nullptr, biasCol, 3 * C, nullptr, 0, 0, 1.0f, 0);

    // 4. v -> vB [B][C][N]
    extract_v<<<dim3(Nn_ / 64, C / 64, Bb_), 256, 0, stream>>>(qkvT, vB);

    // 5. flash attention + merge -> refsT bf16 [B][N][C]
    flash_attn<<<dim3(Nn_ / 64, KVSPLIT, Bb_), 256, 0, stream>>>(qkvT, vB, Opart, mlbuf);
    merge_flash<<<(int)((long)Bb_ * Nn_ * 64 / 256), 256, 0, stream>>>(Opart, mlbuf, refsT);

    // 6. catT[:, :256] = qryT + refsT @ Wproj^T + bproj
    gemm_bt<<<dim3(2, 32, Bb_), 256, 0, stream>>>(
        refsT, Wprojb, nullptr, catT, Nn_, C, C, C, C, 2 * C,
        MN, 0, (long)Nn_ * 2 * C,
        nullptr, bproj, 0, qryT, C, MN, 1.0f, 0);

    // 7. qc = Wq @ x2 + bq   (fp32 [B][HID][N])
    gemm_bt<<<dim3(32, 1, Bb_), 256, 0, stream>>>(
        Wqb, x2T, qc, nullptr, HID, Nn_, C, C, C, Nn_,
        0, MN, (long)HID * Nn_,
        bq, nullptr, 0, nullptr, 0, 0, 1.0f, 0);

    // 8. cross attention -> refcT bf16 [B][N][HID]
    kv_proj_kernel<<<Bb_ * NC, 256, 0, stream>>>(ctx, Wkv, bkv, kvc);
    cross_attn_kernel<<<Bb_ * (Nn_ / 128), 256, 0, stream>>>(qc, kvc, refcT);

    // 9. catT[:, 256:] = qryT + refcT @ Wout^T + bout
    gemm_bt<<<dim3(2, 32, Bb_), 256, 0, stream>>>(
        refcT, Woutb, nullptr, catT + C, Nn_, C, HID, HID, HID, 2 * C,
        (long)Nn_ * HID, 0, (long)Nn_ * 2 * C,
        nullptr, bout, 0, qryT, C, MN, 1.0f, 0);

    // 10. implicit conv3x3 (tap-split) + reduce(relu) -> y1T bf16 [B][N][C]
    conv3x3_gemm<<<dim3(2, 32, Bb_ * 3), 256, 0, stream>>>(catT, Wtap, convPart);
    for (int b = 0; b < Bb_; ++b)
        reduce_partials<<<(int)(MN / 1024), 256, 0, stream>>>(
            convPart + (long)b * 3 * MN, MN, 3, y1T + (long)b * MN, MN, 1);

    // 11. out = qry + Wf2 @ y1 + bf2   (fp32 [B][C][N])
    gemm_bt<<<dim3(32, 2, Bb_), 256, 0, stream>>>(
        Wf2b, y1T, out, nullptr, C, Nn_, C, C, C, Nn_,
        0, MN, CN,
        bf2, nullptr, 0, qry, Nn_, CN, 1.0f, 0);
}

// Round 5
// 384.757 us; speedup vs baseline: 8.3642x; 1.0299x over previous
//
#include <hip/hip_runtime.h>
#include <hip/hip_bf16.h>

#define C 256
#define HID 128
#define Bb_ 2
#define Hh 64
#define Ww 64
#define Nn_ 4096
#define NP 16
#define NC 16
#define KVSPLIT 4

typedef __bf16 bf16x8 __attribute__((ext_vector_type(8)));
typedef float f32x4 __attribute__((ext_vector_type(4)));

// ---------------------------------------------------------------------------
// Coalesced tiled LayerNorm -> x1T, x2T bf16 [B][N][C]
__global__ __launch_bounds__(256) void lnT_kernel(
    const float* __restrict__ x,
    const float* __restrict__ g1, const float* __restrict__ b1,
    const float* __restrict__ g2, const float* __restrict__ b2,
    __hip_bfloat16* __restrict__ x1T, __hip_bfloat16* __restrict__ x2T)
{
    int blk = blockIdx.x;
    int b = blk >> 6;
    int n0 = (blk & 63) << 6;
    int t = threadIdx.x;
    __shared__ __hip_bfloat16 xs[64][258];
    __shared__ float rs4[4][64], rq4[4][64], mean[64], inv[64];
    int j = t & 63, cg = t >> 6;
    float s = 0.f, q = 0.f;
    for (int it = 0; it < 64; ++it) {
        int c = it * 4 + cg;
        float v = x[((long)b * C + c) * Nn_ + n0 + j];
        xs[j][c] = __float2bfloat16(v);
        s += v; q += v * v;
    }
    rs4[cg][j] = s; rq4[cg][j] = q;
    __syncthreads();
    if (t < 64) {
        float S = rs4[0][t] + rs4[1][t] + rs4[2][t] + rs4[3][t];
        float Q = rq4[0][t] + rq4[1][t] + rq4[2][t] + rq4[3][t];
        float m = S * (1.0f / C);
        float var = Q * (1.0f / C) - m * m;
        mean[t] = m; inv[t] = rsqrtf(var + 1e-5f);
    }
    __syncthreads();
    float G1 = g1[t], B1 = b1[t], G2 = g2[t], B2 = b2[t];
    for (int j2 = 0; j2 < 64; ++j2) {
        float v = __bfloat162float(xs[j2][t]);
        float xn = (v - mean[j2]) * inv[j2];
        long o = ((long)b * Nn_ + n0 + j2) * C + t;
        x1T[o] = __float2bfloat16(xn * G1 + B1);
        x2T[o] = __float2bfloat16(xn * G2 + B2);
    }
}

// ---------------------------------------------------------------------------
// qry [B][C][N] fp32 -> qryT [B][N][C] fp32 (64x64 LDS tiles)
__global__ __launch_bounds__(256) void transpose_qry(
    const float* __restrict__ qry, float* __restrict__ qryT)
{
    int b = blockIdx.z;
    int c0 = blockIdx.y * 64, n0 = blockIdx.x * 64;
    __shared__ float tf[64][65];
    int tx = threadIdx.x & 63, tg = threadIdx.x >> 6;
    for (int rr = tg; rr < 64; rr += 4)
        tf[rr][tx] = qry[((long)b * C + c0 + rr) * Nn_ + n0 + tx];
    __syncthreads();
    for (int rr = tg; rr < 64; rr += 4)
        qryT[((long)b * Nn_ + n0 + rr) * C + c0 + tx] = tf[tx][rr];
}

// ---------------------------------------------------------------------------
__global__ __launch_bounds__(256) void gate_kernel(
    const float* __restrict__ arch, const float* __restrict__ Wg,
    const float* __restrict__ bg, float* __restrict__ gate)
{
    int b = blockIdx.x;
    int o = threadIdx.x;
    __shared__ float guide[C];
    float s = 0.f;
    for (int p = 0; p < NP; ++p) s += arch[(long)b * NP * C + (long)p * C + o];
    guide[o] = s * (1.0f / NP);
    __syncthreads();
    float acc = bg[o];
    for (int cc = 0; cc < C; ++cc) acc += guide[cc] * Wg[(long)o * C + cc];
    gate[b * C + o] = 1.0f / (1.0f + __expf(-acc));
}

// ---------------------------------------------------------------------------
// Gated Wqkv bf16 + col bias. q-part (o<C) scaled by log2e/16 so QK^T scores
// arrive in log2 domain (softmax exp becomes a single v_exp_f32).
#define QSCALE 0.09016844005429271f   // log2(e)/16
__global__ __launch_bounds__(256) void build_wqkv(
    const float* __restrict__ Wqkv, const float* __restrict__ bqkv,
    const float* __restrict__ gate,
    __hip_bfloat16* __restrict__ WqkvG, float* __restrict__ biasCol)
{
    long i = (long)blockIdx.x * 256 + threadIdx.x;
    long total = (long)Bb_ * 3 * C * C;
    if (i < total) {
        long b = i / (3 * C * C);
        long rem = i % (3 * C * C);
        int o = (int)(rem / C);
        float v = Wqkv[rem];
        if (o < C) v *= QSCALE;
        else if (o < 2 * C) v *= gate[b * C + (o - C)];
        WqkvG[i] = __float2bfloat16(v);
    }
    if (i < (long)Bb_ * 3 * C) {
        long b = i / (3 * C);
        int o = (int)(i % (3 * C));
        float v = bqkv[o];
        if (o < C) v *= QSCALE;
        else if (o < 2 * C) v *= gate[b * C + (o - C)];
        biasCol[i] = v;
    }
}

// ---------------------------------------------------------------------------
__global__ __launch_bounds__(256) void cast_f2b(
    const float* __restrict__ in, __hip_bfloat16* __restrict__ out, long n)
{
    long i = (long)blockIdx.x * 256 + threadIdx.x;
    if (i < n) out[i] = __float2bfloat16(in[i]);
}

// ---------------------------------------------------------------------------
// Wf1 [O][512][3][3] -> Wtap [9][O][512] bf16
__global__ __launch_bounds__(256) void build_wtap(
    const float* __restrict__ Wf1, __hip_bfloat16* __restrict__ Wtap)
{
    long i = (long)blockIdx.x * 256 + threadIdx.x;
    if (i >= 9l * C * 2 * C) return;
    int tap = (int)(i / (C * 2 * C));
    long rem = i % (C * 2 * C);
    int o = (int)(rem / (2 * C)), ic = (int)(rem % (2 * C));
    Wtap[i] = __float2bfloat16(Wf1[((long)o * 2 * C + ic) * 9 + tap]);
}

// ---------------------------------------------------------------------------
// MFMA bf16 GEMM: D[m][n] = alpha * sum_k A[m*lda+k]*Bt[n*ldb+k] (+biasRow[m])
//                 (+biasCol[n]) (+resid[m*ldr+n]) (relu), out fp32 or bf16.
__global__ __launch_bounds__(256) void gemm_bt(
    const __hip_bfloat16* __restrict__ A,
    const __hip_bfloat16* __restrict__ Bt,
    float* __restrict__ D,
    __hip_bfloat16* __restrict__ Dbf,
    int M, int N, int K, int lda, int ldb, int ldd,
    long batchA, long batchB, long batchD,
    const float* __restrict__ biasRow,
    const float* __restrict__ biasCol, long bcStride,
    const float* __restrict__ resid, int ldr, long batchR,
    float alpha, int relu)
{
    __shared__ __align__(16) __hip_bfloat16 As[128 * 32];
    __shared__ __align__(16) __hip_bfloat16 Bs[128 * 32];
    int bz = blockIdx.z;
    const __hip_bfloat16* Ab = A + (long)bz * batchA;
    const __hip_bfloat16* Bb = Bt + (long)bz * batchB;
    int m0 = blockIdx.y * 128, n0 = blockIdx.x * 128;
    int tid = threadIdx.x;
    int lane = tid & 63, wave = tid >> 6;
    int wr = wave >> 1, wc = wave & 1;
    int lr = lane & 15, lg = lane >> 4;

    f32x4 acc[4][4];
    #pragma unroll
    for (int i = 0; i < 4; ++i)
        #pragma unroll
        for (int j = 0; j < 4; ++j)
            #pragma unroll
            for (int r = 0; r < 4; ++r) acc[i][j][r] = 0.f;

    for (int k0 = 0; k0 < K; k0 += 32) {
        #pragma unroll
        for (int q = 0; q < 2; ++q) {
            int idx = q * 256 + tid;
            int row = idx >> 2;
            int ke = (idx & 3) * 8;
            uint4 va = *(const uint4*)(Ab + (long)(m0 + row) * lda + k0 + ke);
            uint4 vb = *(const uint4*)(Bb + (long)(n0 + row) * ldb + k0 + ke);
            ((uint4*)As)[idx] = va;
            ((uint4*)Bs)[idx] = vb;
        }
        __syncthreads();
        bf16x8 af[4], bfr[4];
        #pragma unroll
        for (int i = 0; i < 4; ++i)
            af[i] = *(const bf16x8*)(As + (wr * 64 + i * 16 + lr) * 32 + lg * 8);
        #pragma unroll
        for (int j = 0; j < 4; ++j)
            bfr[j] = *(const bf16x8*)(Bs + (wc * 64 + j * 16 + lr) * 32 + lg * 8);
        #pragma unroll
        for (int i = 0; i < 4; ++i)
            #pragma unroll
            for (int j = 0; j < 4; ++j)
                acc[i][j] = __builtin_amdgcn_mfma_f32_16x16x32_bf16(af[i], bfr[j], acc[i][j], 0, 0, 0);
        __syncthreads();
    }

    int colc = n0 + wc * 64 + lr;
    #pragma unroll
    for (int i = 0; i < 4; ++i) {
        #pragma unroll
        for (int r = 0; r < 4; ++r) {
            int row = m0 + wr * 64 + i * 16 + lg * 4 + r;
            float brv = biasRow ? biasRow[row] : 0.f;
            #pragma unroll
            for (int j = 0; j < 4; ++j) {
                int cc = colc + j * 16;
                float v = acc[i][j][r] * alpha + brv;
                if (biasCol) v += biasCol[bz * bcStride + cc];
                if (resid) v += resid[(long)bz * batchR + (long)row * ldr + cc];
                if (relu) v = fmaxf(v, 0.f);
                long oa = (long)bz * batchD + (long)row * ldd + cc;
                if (Dbf) Dbf[oa] = __float2bfloat16(v);
                else     D[oa] = v;
            }
        }
    }
}

// ---------------------------------------------------------------------------
// v slice of qkvT -> vB [B][C][N] bf16
__global__ __launch_bounds__(256) void extract_v(
    const __hip_bfloat16* __restrict__ qkvT, __hip_bfloat16* __restrict__ vB)
{
    int b = blockIdx.z;
    int c0 = blockIdx.y * 64, m0 = blockIdx.x * 64;
    __shared__ __hip_bfloat16 tb[64][66];
    int tx = threadIdx.x & 63, tg = threadIdx.x >> 6;
    for (int rr = tg; rr < 64; rr += 4)
        tb[rr][tx] = qkvT[((long)b * Nn_ + m0 + rr) * (3 * C) + 2 * C + c0 + tx];
    __syncthreads();
    for (int rr = tg; rr < 64; rr += 4)
        vB[((long)b * C + c0 + rr) * Nn_ + m0 + tx] = tb[tx][rr];
}

// ---------------------------------------------------------------------------
// Flash attention, NO-MAX variant: scores arrive in log2 domain (q pre-scaled),
// P = exp2(s) directly; row-sum accumulated per-lane, single reduce at end.
// grid (64 Qtiles, KVSPLIT, B), 256 threads (4 waves x 16 Q-rows).
__global__ __launch_bounds__(256) void flash_attn(
    const __hip_bfloat16* __restrict__ qkvT,
    const __hip_bfloat16* __restrict__ vB,
    float* __restrict__ Opart,      // [B][KVSPLIT][N][256] unnormalized
    float* __restrict__ lsum)       // [B][KVSPLIT][N]
{
    int qb = blockIdx.x, sp = blockIdx.y, b = blockIdx.z;
    int n0 = qb * 64;
    int tid = threadIdx.x;
    int lane = tid & 63, w = tid >> 6;
    int lr = lane & 15, lg = lane >> 4;

    __shared__ __align__(16) __hip_bfloat16 KV[256 * 72];    // K:[64][264] / Vt:[256][72]
    __shared__ __align__(16) __hip_bfloat16 Pl[64 * 72];

    bf16x8 qf[8];
    {
        const __hip_bfloat16* qp = qkvT + ((long)b * Nn_ + n0 + w * 16 + lr) * (3 * C);
        #pragma unroll
        for (int ks = 0; ks < 8; ++ks)
            qf[ks] = *(const bf16x8*)(qp + ks * 32 + lg * 8);
    }

    f32x4 Oacc[16];
    #pragma unroll
    for (int jd = 0; jd < 16; ++jd)
        #pragma unroll
        for (int r = 0; r < 4; ++r) Oacc[jd][r] = 0.f;
    float l_r[4] = {0.f, 0.f, 0.f, 0.f};

    int kvBeg = sp * (Nn_ / KVSPLIT);
    for (int t = 0; t < (Nn_ / KVSPLIT) / 64; ++t) {
        int kv0 = kvBeg + t * 64;
        // ---- stage K tile [64][264]
        {
            const __hip_bfloat16* kp = qkvT + ((long)b * Nn_ + kv0) * (3 * C) + C;
            #pragma unroll
            for (int ps = 0; ps < 8; ++ps) {
                int idx = ps * 256 + tid;
                int row = idx >> 5, c8 = idx & 31;
                *(uint4*)(&KV[row * 264 + c8 * 8]) =
                    *(const uint4*)(kp + (long)row * (3 * C) + c8 * 8);
            }
        }
        __syncthreads();
        // ---- S = Q K^T (log2-domain scores)
        f32x4 sacc[4];
        #pragma unroll
        for (int j = 0; j < 4; ++j)
            #pragma unroll
            for (int r = 0; r < 4; ++r) sacc[j][r] = 0.f;
        #pragma unroll
        for (int ks = 0; ks < 8; ++ks) {
            #pragma unroll
            for (int j = 0; j < 4; ++j) {
                bf16x8 kf = *(const bf16x8*)(&KV[(j * 16 + lr) * 264 + ks * 32 + lg * 8]);
                sacc[j] = __builtin_amdgcn_mfma_f32_16x16x32_bf16(qf[ks], kf, sacc[j], 0, 0, 0);
            }
        }
        // ---- P = exp2(S); accumulate row-sum per lane
        #pragma unroll
        for (int j = 0; j < 4; ++j)
            #pragma unroll
            for (int r = 0; r < 4; ++r) {
                float p = __builtin_amdgcn_exp2f(sacc[j][r]);
                l_r[r] += p;
                Pl[(w * 16 + 4 * lg + r) * 72 + j * 16 + lr] = __float2bfloat16(p);
            }
        __syncthreads();   // all waves done reading K
        // ---- stage Vt tile [256][72]
        {
            const __hip_bfloat16* vp = vB + (long)b * C * Nn_ + kv0;
            #pragma unroll
            for (int ps = 0; ps < 8; ++ps) {
                int idx = ps * 256 + tid;
                int row = idx >> 3, c8 = idx & 7;
                *(uint4*)(&KV[row * 72 + c8 * 8]) =
                    *(const uint4*)(vp + (long)row * Nn_ + c8 * 8);
            }
        }
        __syncthreads();
        // ---- O += P V^T
        #pragma unroll
        for (int ks = 0; ks < 2; ++ks) {
            bf16x8 pf = *(const bf16x8*)(&Pl[(w * 16 + lr) * 72 + ks * 32 + lg * 8]);
            #pragma unroll
            for (int jd = 0; jd < 16; ++jd) {
                bf16x8 vf = *(const bf16x8*)(&KV[(jd * 16 + lr) * 72 + ks * 32 + lg * 8]);
                Oacc[jd] = __builtin_amdgcn_mfma_f32_16x16x32_bf16(pf, vf, Oacc[jd], 0, 0, 0);
            }
        }
        __syncthreads();   // before next K staging overwrites Vt
    }

    // final row-sum reduce across the 16 lanes of each row group
    #pragma unroll
    for (int r = 0; r < 4; ++r) {
        float v = l_r[r];
        #pragma unroll
        for (int off = 1; off <= 8; off <<= 1)
            v += __shfl_xor(v, off);
        l_r[r] = v;
    }

    float* Op = Opart + (((long)b * KVSPLIT + sp) * Nn_ + n0) * 256;
    #pragma unroll
    for (int jd = 0; jd < 16; ++jd)
        #pragma unroll
        for (int r = 0; r < 4; ++r) {
            int row = w * 16 + lg * 4 + r;
            Op[(long)row * 256 + jd * 16 + lr] = Oacc[jd][r];
        }
    if (lr == 0) {
        float* lp = lsum + ((long)b * KVSPLIT + sp) * Nn_ + n0;
        #pragma unroll
        for (int r = 0; r < 4; ++r)
            lp[w * 16 + lg * 4 + r] = l_r[r];
    }
}

// ---------------------------------------------------------------------------
// Merge KVSPLIT partials (simple sums) -> refsT bf16 [B][N][256]
__global__ __launch_bounds__(256) void merge_flash(
    const float* __restrict__ Opart, const float* __restrict__ lsum,
    __hip_bfloat16* __restrict__ refsT)
{
    long gi = (long)blockIdx.x * 256 + threadIdx.x;
    long row = gi >> 6;              // over B*N
    int c4 = (int)(gi & 63) * 4;
    long b = row / Nn_, n = row % Nn_;
    float l = 0.f;
    f32x4 o = {0.f, 0.f, 0.f, 0.f};
    #pragma unroll
    for (int sp = 0; sp < KVSPLIT; ++sp) {
        long rr = (b * KVSPLIT + sp) * Nn_ + n;
        l += lsum[rr];
        o += *(const f32x4*)(Opart + rr * 256 + c4);
    }
    float dn = 1.0f / l;
    union { ushort4 u; __hip_bfloat16 h[4]; } cv;
    #pragma unroll
    for (int k = 0; k < 4; ++k)
        cv.h[k] = __float2bfloat16(o[k] * dn);
    *(ushort4*)(refsT + (b * Nn_ + n) * 256 + c4) = cv.u;
}

// ---------------------------------------------------------------------------
// Implicit-GEMM 3x3 conv, tap-split (kh). partials [B][3][N][256] fp32.
__global__ __launch_bounds__(256) void conv3x3_gemm(
    const __hip_bfloat16* __restrict__ catT,   // [B][N][512]
    const __hip_bfloat16* __restrict__ Wtap,   // [9][256][512]
    float* __restrict__ partials)
{
    __shared__ __align__(16) __hip_bfloat16 As[128 * 32];
    __shared__ __align__(16) __hip_bfloat16 Bs[128 * 32];
    int z = blockIdx.z;
    int b = z / 3, sp = z % 3;
    int dh = sp - 1;
    int o0 = blockIdx.x * 128, m0 = blockIdx.y * 128;
    int tid = threadIdx.x;
    int lane = tid & 63, wave = tid >> 6;
    int wr = wave >> 1, wc = wave & 1;
    int lr = lane & 15, lg = lane >> 4;
    const __hip_bfloat16* cb = catT + (long)b * Nn_ * (2 * C);

    f32x4 acc[4][4];
    #pragma unroll
    for (int i = 0; i < 4; ++i)
        #pragma unroll
        for (int j = 0; j < 4; ++j)
            #pragma unroll
            for (int r = 0; r < 4; ++r) acc[i][j][r] = 0.f;

    for (int kw = 0; kw < 3; ++kw) {
        int dw = kw - 1;
        const __hip_bfloat16* wt = Wtap + (long)(sp * 3 + kw) * C * (2 * C);
        for (int k0 = 0; k0 < 2 * C; k0 += 32) {
            #pragma unroll
            for (int q = 0; q < 2; ++q) {
                int idx = q * 256 + tid;
                int row = idx >> 2;
                int ke = (idx & 3) * 8;
                int gm = m0 + row;
                int h = (gm >> 6) + dh, w2 = (gm & 63) + dw;
                uint4 va = {0, 0, 0, 0};
                if ((unsigned)h < 64u && (unsigned)w2 < 64u)
                    va = *(const uint4*)(cb + ((long)((h << 6) + w2)) * (2 * C) + k0 + ke);
                ((uint4*)As)[idx] = va;
                ((uint4*)Bs)[idx] = *(const uint4*)(wt + (long)(o0 + row) * (2 * C) + k0 + ke);
            }
            __syncthreads();
            bf16x8 af[4], bfr[4];
            #pragma unroll
            for (int i = 0; i < 4; ++i)
                af[i] = *(const bf16x8*)(As + (wr * 64 + i * 16 + lr) * 32 + lg * 8);
            #pragma unroll
            for (int j = 0; j < 4; ++j)
                bfr[j] = *(const bf16x8*)(Bs + (wc * 64 + j * 16 + lr) * 32 + lg * 8);
            #pragma unroll
            for (int i = 0; i < 4; ++i)
                #pragma unroll
                for (int j = 0; j < 4; ++j)
                    acc[i][j] = __builtin_amdgcn_mfma_f32_16x16x32_bf16(af[i], bfr[j], acc[i][j], 0, 0, 0);
            __syncthreads();
        }
    }

    float* Dp = partials + ((long)(b * 3 + sp) * Nn_ + m0) * 256;
    #pragma unroll
    for (int i = 0; i < 4; ++i)
        #pragma unroll
        for (int r = 0; r < 4; ++r) {
            int row = wr * 64 + i * 16 + lg * 4 + r;
            #pragma unroll
            for (int j = 0; j < 4; ++j)
                Dp[(long)row * 256 + o0 + wc * 64 + j * 16 + lr] = acc[i][j][r];
        }
}

// ---------------------------------------------------------------------------
__global__ __launch_bounds__(256) void reduce_partials(
    const float* __restrict__ part, long partStride, int splits,
    __hip_bfloat16* __restrict__ out, long n, int relu)
{
    long i = ((long)blockIdx.x * 256 + threadIdx.x) * 4;
    if (i >= n) return;
    f32x4 s = *(const f32x4*)(part + i);
    for (int sp = 1; sp < splits; ++sp)
        s += *(const f32x4*)(part + (long)sp * partStride + i);
    union { ushort4 u; __hip_bfloat16 h[4]; } cv;
    #pragma unroll
    for (int k = 0; k < 4; ++k) {
        float v = s[k];
        if (relu) v = fmaxf(v, 0.f);
        cv.h[k] = __float2bfloat16(v);
    }
    *(ushort4*)(out + i) = cv.u;
}

// ---------------------------------------------------------------------------
__global__ __launch_bounds__(256) void kv_proj_kernel(
    const float* __restrict__ ctx, const float* __restrict__ Wkv,
    const float* __restrict__ bkv, float* __restrict__ kvc)
{
    int b = blockIdx.x / NC, i = blockIdx.x % NC;
    int j = threadIdx.x;
    const float* cv = ctx + ((long)b * NC + i) * C;
    __shared__ float cs[C];
    cs[j] = cv[j];
    __syncthreads();
    float acc = bkv[j];
    for (int cc = 0; cc < C; ++cc) acc += cs[cc] * Wkv[(long)j * C + cc];
    int half = j / HID, h = j % HID;
    kvc[((long)b * 2 + half) * HID * NC + (long)h * NC + i] = acc;
}

// ---------------------------------------------------------------------------
__global__ __launch_bounds__(256) void cross_attn_kernel(
    const float* __restrict__ qc, const float* __restrict__ kvc,
    __hip_bfloat16* __restrict__ refcT)
{
    int blk = blockIdx.x;
    int b = blk / (Nn_ / 128);
    long n0 = (long)(blk % (Nn_ / 128)) * 128;
    int t = threadIdx.x;
    __shared__ float kl[HID][NC], vl[HID][NC];
    __shared__ __hip_bfloat16 refl[128][HID + 2];
    const float* kb = kvc + (long)b * 2 * HID * NC;
    for (int l = t; l < HID * NC; l += 256) {
        kl[l / NC][l % NC] = kb[l];
        vl[l / NC][l % NC] = kb[HID * NC + l];
    }
    __syncthreads();
    if (t < 128) {
        long n = n0 + t;
        float s[NC];
        #pragma unroll
        for (int m = 0; m < NC; ++m) s[m] = 0.f;
        for (int h = 0; h < HID; ++h) {
            float qh = qc[(long)b * HID * Nn_ + (long)h * Nn_ + n];
            #pragma unroll
            for (int m = 0; m < NC; ++m) s[m] += qh * kl[h][m];
        }
        const float scc = 0.08838834764831845f;
        float mx = -1e30f;
        #pragma unroll
        for (int m = 0; m < NC; ++m) { s[m] *= scc; mx = fmaxf(mx, s[m]); }
        float sum = 0.f;
        #pragma unroll
        for (int m = 0; m < NC; ++m) { s[m] = __expf(s[m] - mx); sum += s[m]; }
        float inv = 1.0f / sum;
        for (int h = 0; h < HID; ++h) {
            float acc = 0.f;
            #pragma unroll
            for (int m = 0; m < NC; ++m) acc += vl[h][m] * s[m];
            refl[t][h] = __float2bfloat16(acc * inv);
        }
    }
    __syncthreads();
    for (int it = 0; it < 64; ++it) {
        int r = it * 2 + (t >> 7);
        int h = t & 127;
        refcT[((long)b * Nn_ + n0 + r) * HID + h] = refl[r][h];
    }
}

// ---------------------------------------------------------------------------
extern "C" void kernel_launch(void* const* d_in, const int* in_sizes, int n_in,
                              void* d_out, int out_size, void* d_ws, size_t ws_size,
                              hipStream_t stream)
{
    const float* qry   = (const float*)d_in[0];
    const float* arch  = (const float*)d_in[1];
    const float* ctx   = (const float*)d_in[2];
    const float* ln1_g = (const float*)d_in[3];
    const float* ln1_b = (const float*)d_in[4];
    const float* Wqkv  = (const float*)d_in[5];
    const float* bqkv  = (const float*)d_in[6];
    const float* Wproj = (const float*)d_in[7];
    const float* bproj = (const float*)d_in[8];
    const float* Wg    = (const float*)d_in[9];
    const float* bg    = (const float*)d_in[10];
    const float* ln2_g = (const float*)d_in[11];
    const float* ln2_b = (const float*)d_in[12];
    const float* Wq    = (const float*)d_in[13];
    const float* bq    = (const float*)d_in[14];
    const float* Wkv   = (const float*)d_in[15];
    const float* bkv   = (const float*)d_in[16];
    const float* Wout  = (const float*)d_in[17];
    const float* bout  = (const float*)d_in[18];
    const float* Wf1   = (const float*)d_in[19];
    const float* Wf2   = (const float*)d_in[20];
    const float* bf2   = (const float*)d_in[21];
    float* out = (float*)d_out;

    const long CN = (long)C * Nn_;
    const long MN = (long)Nn_ * C;
    char* ws = (char*)d_ws;
    size_t off = 0;
    auto alloc = [&](size_t bytes) -> char* {
        char* p = ws + off;
        off += (bytes + 255) & ~size_t(255);
        return p;
    };
    float* qryT     = (float*)alloc(Bb_ * MN * 4);
    float* Opart    = (float*)alloc((long)Bb_ * KVSPLIT * MN * 4);       // 32MB
    float* lbuf     = (float*)alloc((long)Bb_ * KVSPLIT * Nn_ * 4);
    float* convPart = (float*)alloc((long)Bb_ * 3 * MN * 4);             // 24MB
    float* qc       = (float*)alloc((long)Bb_ * HID * Nn_ * 4);
    float* kvc      = (float*)alloc((long)Bb_ * 2 * HID * NC * 4);
    float* gate     = (float*)alloc(Bb_ * C * 4);
    float* biasCol  = (float*)alloc((long)Bb_ * 3 * C * 4);
    __hip_bfloat16* x1T   = (__hip_bfloat16*)alloc(Bb_ * MN * 2);
    __hip_bfloat16* x2T   = (__hip_bfloat16*)alloc(Bb_ * MN * 2);
    __hip_bfloat16* qkvT  = (__hip_bfloat16*)alloc((long)Bb_ * Nn_ * 3 * C * 2);
    __hip_bfloat16* vB    = (__hip_bfloat16*)alloc(Bb_ * CN * 2);
    __hip_bfloat16* refsT = (__hip_bfloat16*)alloc(Bb_ * MN * 2);
    __hip_bfloat16* refcT = (__hip_bfloat16*)alloc((long)Bb_ * Nn_ * HID * 2);
    __hip_bfloat16* catT  = (__hip_bfloat16*)alloc((long)Bb_ * Nn_ * 2 * C * 2);
    __hip_bfloat16* y1T   = (__hip_bfloat16*)alloc(Bb_ * MN * 2);
    __hip_bfloat16* WqkvG = (__hip_bfloat16*)alloc((long)Bb_ * 3 * C * C * 2);
    __hip_bfloat16* Wprojb= (__hip_bfloat16*)alloc((long)C * C * 2);
    __hip_bfloat16* Wqb   = (__hip_bfloat16*)alloc((long)HID * C * 2);
    __hip_bfloat16* Woutb = (__hip_bfloat16*)alloc((long)C * HID * 2);
    __hip_bfloat16* Wtap  = (__hip_bfloat16*)alloc((long)9 * C * 2 * C * 2);
    __hip_bfloat16* Wf2b  = (__hip_bfloat16*)alloc((long)C * C * 2);

    // 1. layernorm + qry transpose
    lnT_kernel<<<Bb_ * (Nn_ / 64), 256, 0, stream>>>(qry, ln1_g, ln1_b, ln2_g, ln2_b, x1T, x2T);
    transpose_qry<<<dim3(Nn_ / 64, C / 64, Bb_), 256, 0, stream>>>(qry, qryT);

    // 2. gate + weight prep
    gate_kernel<<<Bb_, 256, 0, stream>>>(arch, Wg, bg, gate);
    build_wqkv<<<(Bb_ * 3 * C * C + 255) / 256, 256, 0, stream>>>(Wqkv, bqkv, gate, WqkvG, biasCol);
    cast_f2b<<<(C * C + 255) / 256, 256, 0, stream>>>(Wproj, Wprojb, (long)C * C);
    cast_f2b<<<(HID * C + 255) / 256, 256, 0, stream>>>(Wq, Wqb, (long)HID * C);
    cast_f2b<<<(C * HID + 255) / 256, 256, 0, stream>>>(Wout, Woutb, (long)C * HID);
    cast_f2b<<<(C * C + 255) / 256, 256, 0, stream>>>(Wf2, Wf2b, (long)C * C);
    build_wtap<<<((long)9 * C * 2 * C + 255) / 256, 256, 0, stream>>>(Wf1, Wtap);

    // 3. qkvT = x1T @ WqkvG^T + biasCol  -> bf16 [B][N][768]
    gemm_bt<<<dim3(6, 32, Bb_), 256, 0, stream>>>(
        x1T, WqkvG, nullptr, qkvT, Nn_, 3 * C, C, C, C, 3 * C,
        MN, (long)3 * C * C, (long)Nn_ * 3 * C,
        nullptr, biasCol, 3 * C, nullptr, 0, 0, 1.0f, 0);

    // 4. v -> vB [B][C][N]
    extract_v<<<dim3(Nn_ / 64, C / 64, Bb_), 256, 0, stream>>>(qkvT, vB);

    // 5. flash attention (no-max) + merge -> refsT bf16 [B][N][C]
    flash_attn<<<dim3(Nn_ / 64, KVSPLIT, Bb_), 256, 0, stream>>>(qkvT, vB, Opart, lbuf);
    merge_flash<<<(int)((long)Bb_ * Nn_ * 64 / 256), 256, 0, stream>>>(Opart, lbuf, refsT);

    // 6. catT[:, :256] = qryT + refsT @ Wproj^T + bproj
    gemm_bt<<<dim3(2, 32, Bb_), 256, 0, stream>>>(
        refsT, Wprojb, nullptr, catT, Nn_, C, C, C, C, 2 * C,
        MN, 0, (long)Nn_ * 2 * C,
        nullptr, bproj, 0, qryT, C, MN, 1.0f, 0);

    // 7. qc = Wq @ x2 + bq   (fp32 [B][HID][N])
    gemm_bt<<<dim3(32, 1, Bb_), 256, 0, stream>>>(
        Wqb, x2T, qc, nullptr, HID, Nn_, C, C, C, Nn_,
        0, MN, (long)HID * Nn_,
        bq, nullptr, 0, nullptr, 0, 0, 1.0f, 0);

    // 8. cross attention -> refcT bf16 [B][N][HID]
    kv_proj_kernel<<<Bb_ * NC, 256, 0, stream>>>(ctx, Wkv, bkv, kvc);
    cross_attn_kernel<<<Bb_ * (Nn_ / 128), 256, 0, stream>>>(qc, kvc, refcT);

    // 9. catT[:, 256:] = qryT + refcT @ Wout^T + bout
    gemm_bt<<<dim3(2, 32, Bb_), 256, 0, stream>>>(
        refcT, Woutb, nullptr, catT + C, Nn_, C, HID, HID, HID, 2 * C,
        (long)Nn_ * HID, 0, (long)Nn_ * 2 * C,
        nullptr, bout, 0, qryT, C, MN, 1.0f, 0);

    // 10. implicit conv3x3 (tap-split) + reduce(relu) -> y1T bf16 [B][N][C]
    conv3x3_gemm<<<dim3(2, 32, Bb_ * 3), 256, 0, stream>>>(catT, Wtap, convPart);
    for (int b = 0; b < Bb_; ++b)
        reduce_partials<<<(int)(MN / 1024), 256, 0, stream>>>(
            convPart + (long)b * 3 * MN, MN, 3, y1T + (long)b * MN, MN, 1);

    // 11. out = qry + Wf2 @ y1 + bf2   (fp32 [B][C][N])
    gemm_bt<<<dim3(32, 2, Bb_), 256, 0, stream>>>(
        Wf2b, y1T, out, nullptr, C, Nn_, C, C, C, Nn_,
        0, MN, CN,
        bf2, nullptr, 0, qry, Nn_, CN, 1.0f, 0);
}